// Round 1
// 1313.067 us; speedup vs baseline: 1.2428x; 1.2428x over previous
//
#include <hip/hip_runtime.h>
#include <hip/hip_bf16.h>
#include <cstdint>

#define NHW 65536
#define NSQ 32768

// workspace layout (float slots)
static constexpr size_t OFF_AQ  = 0;          // (4,64,256,128) conv1x1_q at nonanchor (squeezed)
static constexpr size_t OFF_AK  = 8388608;    // (4,64,256,128) conv1x1_k at anchor (squeezed)
static constexpr size_t OFF_AV  = 16777216;   // (4,64,256,256) conv1x1_v full res
static constexpr size_t OFF_EK  = 33554432;   // (4,64,256,128) exp(k_dw) squeezed
static constexpr size_t OFF_VD  = 41943040;   // (4,64,256,128) v_dw squeezed
static constexpr size_t OFF_ATT = 50331648;   // bf16 (4,256,128,64) att squeezed, channel-innermost
static constexpr size_t OFF_CTX = 58720256;   // 4*4*16*16
static constexpr size_t OFF_Z   = 58724352;   // 4*64
static constexpr size_t OFF_RWT = 58724608;   // bf16 wA[tap(25)][c/8(8)][o(128)][c%8(8)] = 204800 ushorts
static constexpr size_t MB2_US  = 67108864;   // ushort offset of mbuf2 (mbuf at 0) - phases don't overlap

typedef __attribute__((ext_vector_type(8))) short short8;
typedef __attribute__((ext_vector_type(4))) float floatx4;

// tap tables: first 13 = even parity (kh+kw even), last 12 = odd parity
__device__ __constant__ int TKH[25] = {0,0,0,1,1,2,2,2,3,3,4,4,4,  0,0,1,1,1,2,2,3,3,3,4,4};
__device__ __constant__ int TKW[25] = {0,2,4,1,3,0,2,4,1,3,0,2,4,  1,3,0,2,4,1,3,0,2,4,1,3};

__device__ __forceinline__ float geluf(float x) {
  return 0.5f * x * (1.0f + erff(x * 0.70710678118654752440f));
}
__device__ __forceinline__ unsigned short f2bf(float f) {
  union { float f; uint32_t u; } v; v.f = f;
  uint32_t x = v.u;
  uint32_t r = x + 0x7fffu + ((x >> 16) & 1u);
  return (unsigned short)(r >> 16);
}
__device__ __forceinline__ float bf2f(unsigned short u) {
  union { uint32_t i; float f; } v; v.i = ((uint32_t)u) << 16; return v.f;
}

// K0: prep conv5 weights into A-fragment order: wA[tap][c/8][o][c%8] bf16
__global__ void __launch_bounds__(256) k0_wprep(const float* __restrict__ rw,
                                                unsigned short* __restrict__ wAu) {
  int idx = blockIdx.x * 256 + threadIdx.x;   // 204800 total
  int cj = idx & 7, o = (idx >> 3) & 127, chunk = (idx >> 10) & 7, tap = idx >> 13;
  int c = chunk * 8 + cj;
  int t = TKH[tap] * 5 + TKW[tap];
  wAu[idx] = f2bf(rw[(o * 64 + c) * 25 + t]);
}

// K1: 1x1 convs. q at nonanchor((i+j)%2==0), k at anchor, v everywhere.
__global__ void __launch_bounds__(256) k1_qkv(
    const float* __restrict__ x1, const float* __restrict__ x2,
    const float* __restrict__ q1w, const float* __restrict__ q1b,
    const float* __restrict__ k1w, const float* __restrict__ k1b,
    const float* __restrict__ v1w, const float* __restrict__ v1b,
    float* ws) {
  __shared__ float wq[4096], wk[4096], wv[4096];
  int tid = threadIdx.x;
  for (int idx = tid; idx < 4096; idx += 256) {
    int o = idx >> 6, c = idx & 63;        // coalesced global reads
    wq[c * 64 + o] = q1w[o * 64 + c];
    wk[c * 64 + o] = k1w[o * 64 + c];
    wv[c * 64 + o] = v1w[o * 64 + c];
  }
  __syncthreads();
  int b = blockIdx.x >> 8, i = blockIdx.x & 255;
  int w = tid >> 6, l = tid & 63;
  int j = (((w >> 1) * 64 + l) << 1) | (w & 1);  // wave-uniform column parity
  int par = (i + j) & 1;                          // 1 = anchor -> k
  const float* wsel = par ? wk : wq;
  const float* bsel = par ? k1b : q1b;
  float acc[64];
#pragma unroll
  for (int o = 0; o < 64; o++) acc[o] = bsel[o];
  const float* xp = x1 + ((size_t)b * 64) * NHW + i * 256 + j;
  for (int c = 0; c < 64; c++) {
    float v = xp[(size_t)c * NHW];
    const float* wr = wsel + c * 64;
#pragma unroll
    for (int o = 0; o < 64; o++) acc[o] += wr[o] * v;
  }
  {
    float* dst = ws + (par ? OFF_AK : OFF_AQ) + ((size_t)b * 64) * NSQ + i * 128 + (j >> 1);
#pragma unroll
    for (int o = 0; o < 64; o++) dst[(size_t)o * NSQ] = acc[o];
  }
#pragma unroll
  for (int o = 0; o < 64; o++) acc[o] = v1b[o];
  const float* xp2 = x2 + ((size_t)b * 64) * NHW + i * 256 + j;
  for (int c = 0; c < 64; c++) {
    float v = xp2[(size_t)c * NHW];
    const float* wr = wv + c * 64;
#pragma unroll
    for (int o = 0; o < 64; o++) acc[o] += wr[o] * v;
  }
  float* dv = ws + OFF_AV + ((size_t)b * 64) * NHW + i * 256 + j;
#pragma unroll
  for (int o = 0; o < 64; o++) dv[(size_t)o * NHW] = acc[o];
}

// K2: k depthwise (5 real taps + bias correction) -> exp; v depthwise (9 taps, full res);
// accumulate Z[b,c] = sum exp(kdw)
__global__ void __launch_bounds__(256) k2_dw(
    float* ws,
    const float* __restrict__ kw2, const float* __restrict__ kb2, const float* __restrict__ kb1,
    const float* __restrict__ vw2, const float* __restrict__ vb2) {
  int bid = blockIdx.x;                 // 4*64*128
  int b = bid >> 13, c = (bid >> 7) & 63, ip = bid & 127;
  int tid = threadIdx.x;
  int i = ip * 2 + (tid >> 7);
  int jp = tid & 127;
  int s = 1 - (i & 1);                  // anchor: col = 2*jp + s
  int j = 2 * jp + s;
  const float* AK = ws + OFF_AK + ((size_t)(b * 64 + c)) * NSQ;
  const float* w9 = kw2 + c * 9;
  float acc = kb2[c] + w9[4] * AK[i * 128 + jp];
  int cl = jp - 1 + s, cr = jp + s;
  if (i > 0) {
    const float* r = AK + (i - 1) * 128;
    if (cl >= 0)   acc += w9[0] * r[cl];
    if (cr <= 127) acc += w9[2] * r[cr];
  }
  if (i < 255) {
    const float* r = AK + (i + 1) * 128;
    if (cl >= 0)   acc += w9[6] * r[cl];
    if (cr <= 127) acc += w9[8] * r[cr];
  }
  float bs = 0.f;
  if (i > 0)   bs += w9[1];
  if (i < 255) bs += w9[7];
  if (j > 0)   bs += w9[3];
  if (j < 255) bs += w9[5];
  acc += kb1[c] * bs;                   // masked neighbors contribute conv1 bias only
  float ek = expf(acc);
  ws[OFF_EK + ((size_t)(b * 64 + c)) * NSQ + i * 128 + jp] = ek;

  const float* AV = ws + OFF_AV + ((size_t)(b * 64 + c)) * NHW;
  const float* vw = vw2 + c * 9;
  float av = vb2[c];
#pragma unroll
  for (int kh = 0; kh < 3; kh++) {
    int r = i - 1 + kh;
    if (r < 0 || r > 255) continue;
    const float* rp = AV + r * 256;
#pragma unroll
    for (int kwd = 0; kwd < 3; kwd++) {
      int u = j - 1 + kwd;
      if (u < 0 || u > 255) continue;
      av += vw[kh * 3 + kwd] * rp[u];
    }
  }
  ws[OFF_VD + ((size_t)(b * 64 + c)) * NSQ + i * 128 + jp] = av;

  __shared__ float red[256];
  red[tid] = ek;
  __syncthreads();
#pragma unroll
  for (int off = 128; off > 0; off >>= 1) {
    if (tid < off) red[tid] += red[tid + off];
    __syncthreads();
  }
  if (tid == 0) atomicAdd(ws + OFF_Z + (b * 64 + c), red[0]);
}

// K3: ctx_raw[b,h,d,e] = sum_n ek[b,h*16+d,n] * vdw[b,h*16+e,n]
__global__ void __launch_bounds__(256) k3_ctx(float* ws) {
  int bid = blockIdx.x;                 // 4*4*8
  int b = bid >> 5, h = (bid >> 3) & 3, ch = bid & 7;
  int n0 = ch * 4096;
  int tid = threadIdx.x;
  int d = tid >> 4, e = tid & 15;
  __shared__ float ekt[16][260];
  __shared__ float vdt[16][260];
  const float* ekb = ws + OFF_EK + ((size_t)(b * 64 + h * 16)) * NSQ + n0;
  const float* vdb = ws + OFF_VD + ((size_t)(b * 64 + h * 16)) * NSQ + n0;
  float acc = 0.f;
  for (int sub = 0; sub < 16; sub++) {
    __syncthreads();
#pragma unroll
    for (int r = 0; r < 16; r++) {
      ekt[r][tid] = ekb[(size_t)r * NSQ + sub * 256 + tid];
      vdt[r][tid] = vdb[(size_t)r * NSQ + sub * 256 + tid];
    }
    __syncthreads();
#pragma unroll 8
    for (int x = 0; x < 256; x++) acc += ekt[d][x] * vdt[e][x];
  }
  atomicAdd(ws + OFF_CTX + ((b * 4 + h) * 16 + d) * 16 + e, acc);
}

// K4: q depthwise + softmax over d, att[e] = sum_d (ctx_raw/Z)[d,e]*qsoft[d];
// store bf16, channel-innermost [b][i][jp][c]
__global__ void __launch_bounds__(256) k4_att(
    float* ws,
    const float* __restrict__ qw2, const float* __restrict__ qb2, const float* __restrict__ qb1) {
  int b = blockIdx.x >> 7, ip = blockIdx.x & 127;
  int tid = threadIdx.x;
  int i = ip * 2 + (tid >> 7);
  int jp = tid & 127;
  __shared__ float ctxn[1024];
  for (int idx = tid; idx < 1024; idx += 256)
    ctxn[idx] = ws[OFF_CTX + b * 1024 + idx] / ws[OFF_Z + b * 64 + (idx >> 4)];
  __syncthreads();
  int s = i & 1;                        // nonanchor: col = 2*jp + s
  int j = 2 * jp + s;
  int cl = jp - 1 + s, cr = jp + s;
  unsigned short* attB = (unsigned short*)(ws + OFF_ATT);
  unsigned short* dstp = attB + (((size_t)(b * 256 + i)) * 128 + jp) * 64;
  for (int h = 0; h < 4; h++) {
    float qv[16];
#pragma unroll
    for (int dc = 0; dc < 16; dc++) {
      int c = h * 16 + dc;
      const float* AQ = ws + OFF_AQ + ((size_t)(b * 64 + c)) * NSQ;
      const float* w9 = qw2 + c * 9;
      float acc = qb2[c] + w9[4] * AQ[i * 128 + jp];
      if (i > 0) {
        const float* r = AQ + (i - 1) * 128;
        if (cl >= 0)   acc += w9[0] * r[cl];
        if (cr <= 127) acc += w9[2] * r[cr];
      }
      if (i < 255) {
        const float* r = AQ + (i + 1) * 128;
        if (cl >= 0)   acc += w9[6] * r[cl];
        if (cr <= 127) acc += w9[8] * r[cr];
      }
      float bs = 0.f;
      if (i > 0)   bs += w9[1];
      if (i < 255) bs += w9[7];
      if (j > 0)   bs += w9[3];
      if (j < 255) bs += w9[5];
      qv[dc] = acc + qb1[c] * bs;
    }
    float mx = qv[0];
#pragma unroll
    for (int dc = 1; dc < 16; dc++) mx = fmaxf(mx, qv[dc]);
    float sum = 0.f;
#pragma unroll
    for (int dc = 0; dc < 16; dc++) { qv[dc] = expf(qv[dc] - mx); sum += qv[dc]; }
    float inv = 1.0f / sum;
#pragma unroll
    for (int e = 0; e < 16; e++) {
      float a = 0.f;
#pragma unroll
      for (int dc = 0; dc < 16; dc++) a += ctxn[h * 256 + dc * 16 + e] * qv[dc];
      dstp[h * 16 + e] = f2bf(a * inv);
    }
  }
}

// K5: 5x5 conv 64->128ch over checkerboard-sparse att, as bf16 MFMA implicit GEMM.
// Per (b, parity): C[o=128][n=128 px (4 rows x 32 jp)] = sum_{tap,c} W[o][tap,c]*Att[tap,c][n].
// attL layout [lr(8)][cb(3)][pos(16)][slot=chunk^(pos&7)][8ch] -> conflict-free b128 r/w.
__global__ void __launch_bounds__(256) k5_mfma(
    const unsigned short* __restrict__ attB, const unsigned short* __restrict__ wAu,
    const float* __restrict__ rb, float* __restrict__ out) {
  int p = blockIdx.y, b = blockIdx.z;
  int i0 = (blockIdx.x >> 2) * 4;
  int jp0 = (blockIdx.x & 3) * 32;
  int tid = threadIdx.x;
  int wv = tid >> 6, lane = tid & 63;
  int mh = wv & 1, nh = wv >> 1;
  int l15 = lane & 15, quad = lane >> 4;

  __shared__ __align__(16) unsigned short attL[24576];  // 48KB: X16=((lr*3+cb)*16+pos)*8+slot
  __shared__ __align__(16) unsigned short wL[8192];     // 16KB: X16=(chalf*4+quad)*128+o

  // stage att tile (8 rows x 48 cols x 64 ch): 3072 16B units
  const unsigned short* attBase = attB + ((size_t)b * 256) * 128 * 64;
  for (int k = 0; k < 12; k++) {
    int u = k * 256 + tid;
    int chunk = u & 7;
    int pos = (u >> 3) & 15;
    int cbr = u >> 7;                  // lr*3+cb, 0..23
    int cb = cbr % 3, lr = cbr / 3;
    int r = i0 - 2 + lr;
    int jp = jp0 - 2 + cb * 16 + pos;
    short8 v = {0, 0, 0, 0, 0, 0, 0, 0};
    if (r >= 0 && r < 256 && jp >= 0 && jp < 128)
      v = *(const short8*)(attBase + (((size_t)r * 128) + jp) * 64 + chunk * 8);
    int slot = chunk ^ (pos & 7);
    *(short8*)(attL + (((size_t)cbr * 16 + pos) * 8 + slot) * 8) = v;
  }

  floatx4 acc[16];
#pragma unroll
  for (int x = 0; x < 16; x++) acc[x] = floatx4{0.f, 0.f, 0.f, 0.f};

  int riv[4], ci2[4];
#pragma unroll
  for (int nt = 0; nt < 4; nt++) {
    int ntg = nh * 4 + nt;
    riv[nt] = ntg >> 1;
    ci2[nt] = (ntg & 1) * 16 + l15 + 2;
  }

  int t0 = p ? 13 : 0;
  int ntaps = p ? 12 : 13;
  for (int tt = 0; tt < ntaps; tt++) {
    int tap = t0 + tt;
    int kh = TKH[tap], kw = TKW[tap];
    __syncthreads();
    {
      const short8* src = (const short8*)(wAu + (size_t)tap * 8192);
      short8* dst = (short8*)wL;
#pragma unroll
      for (int k = 0; k < 4; k++) dst[k * 256 + tid] = src[k * 256 + tid];
    }
    __syncthreads();
#pragma unroll
    for (int chalf = 0; chalf < 2; chalf++) {
      short8 a[4], bf[4];
#pragma unroll
      for (int mt = 0; mt < 4; mt++)
        a[mt] = *(const short8*)(wL + (((chalf * 4 + quad) * 128) + mh * 64 + mt * 16 + l15) * 8);
#pragma unroll
      for (int nt = 0; nt < 4; nt++) {
        int lr = riv[nt] + kh;
        int off = ((kw - 2) + ((p + riv[nt]) & 1) - ((riv[nt] + kh) & 1)) >> 1;
        int lc = ci2[nt] + off;
        int cb = lc >> 4, pos = lc & 15;
        int slot = (chalf * 4 + quad) ^ (pos & 7);
        bf[nt] = *(const short8*)(attL + ((((lr * 3 + cb) * 16 + pos) * 8) + slot) * 8);
      }
#pragma unroll
      for (int mt = 0; mt < 4; mt++)
#pragma unroll
        for (int nt = 0; nt < 4; nt++)
          acc[mt * 4 + nt] =
              __builtin_amdgcn_mfma_f32_16x16x32_bf16(a[mt], bf[nt], acc[mt * 4 + nt], 0, 0, 0);
    }
  }

  // epilogue: D row = o = mh*64+mt*16+quad*4+reg, col = n = lane&15 within n-tile
#pragma unroll
  for (int mt = 0; mt < 4; mt++) {
#pragma unroll
    for (int nt = 0; nt < 4; nt++) {
      int ntg = nh * 4 + nt;
      int i = i0 + (ntg >> 1);
      int jp = jp0 + (ntg & 1) * 16 + l15;
      int j = 2 * jp + ((p + i) & 1);
      floatx4 v = acc[mt * 4 + nt];
#pragma unroll
      for (int r = 0; r < 4; r++) {
        int o = mh * 64 + mt * 16 + quad * 4 + r;
        out[(((size_t)(b * 128 + o)) * 256 + i) * 256 + j] = v[r] + rb[o];
      }
    }
  }
}

// K6: m1 = gelu(conv1x1 128->256) ; fp32 in (d_out), bf16 out
__global__ void __launch_bounds__(256) k6_m1(
    const float* __restrict__ attn, const float* __restrict__ m1w, const float* __restrict__ m1b,
    unsigned short* __restrict__ mb) {
  int n0 = blockIdx.x * 64;
  int og = blockIdx.y, b = blockIdx.z;
  int tid = threadIdx.x;
  int ot = tid >> 4, pt = tid & 15;
  __shared__ __align__(16) float aL[2048];
  __shared__ __align__(16) float wL[32 * 68];
  float acc[4][4];
#pragma unroll
  for (int x = 0; x < 4; x++)
#pragma unroll
    for (int y = 0; y < 4; y++) acc[x][y] = 0.f;
  for (int cc = 0; cc < 128; cc += 32) {
    __syncthreads();
#pragma unroll
    for (int k = 0; k < 8; k++) {
      int idx = k * 256 + tid;
      int ci = idx >> 6, pp = idx & 63;
      aL[ci * 64 + pp] = attn[((size_t)(b * 128 + cc + ci)) * NHW + n0 + pp];
      int o = idx >> 5, ci2 = idx & 31;
      wL[ci2 * 68 + o] = m1w[(og * 64 + o) * 128 + cc + ci2];
    }
    __syncthreads();
    for (int ci = 0; ci < 32; ci++) {
      float4 a4 = *(const float4*)(aL + ci * 64 + pt * 4);
      float4 w4 = *(const float4*)(wL + ci * 68 + ot * 4);
      acc[0][0] += w4.x * a4.x; acc[0][1] += w4.x * a4.y; acc[0][2] += w4.x * a4.z; acc[0][3] += w4.x * a4.w;
      acc[1][0] += w4.y * a4.x; acc[1][1] += w4.y * a4.y; acc[1][2] += w4.y * a4.z; acc[1][3] += w4.y * a4.w;
      acc[2][0] += w4.z * a4.x; acc[2][1] += w4.z * a4.y; acc[2][2] += w4.z * a4.z; acc[2][3] += w4.z * a4.w;
      acc[3][0] += w4.w * a4.x; acc[3][1] += w4.w * a4.y; acc[3][2] += w4.w * a4.z; acc[3][3] += w4.w * a4.w;
    }
  }
#pragma unroll
  for (int oi = 0; oi < 4; oi++) {
    int o = og * 64 + ot * 4 + oi;
    float bo = m1b[o];
    ushort4 u;
    u.x = f2bf(geluf(acc[oi][0] + bo));
    u.y = f2bf(geluf(acc[oi][1] + bo));
    u.z = f2bf(geluf(acc[oi][2] + bo));
    u.w = f2bf(geluf(acc[oi][3] + bo));
    *(ushort4*)(mb + ((size_t)(b * 256 + o)) * NHW + n0 + pt * 4) = u;
  }
}

// K7: m2 = gelu(depthwise 3x3 on 256ch), bf16 -> bf16.
// Register-blocked: each thread owns a 4-row x 8-col patch; loads its 6 input
// rows as one short8 + 2 edge scalars each (vs 9 scalar loads/pixel before).
// Block covers 32 rows x 256 cols of one (b,c) plane; row re-read factor 1.5x.
__global__ void __launch_bounds__(256) k7_m2(
    const unsigned short* __restrict__ mb, const float* __restrict__ m2w,
    const float* __restrict__ m2b, unsigned short* __restrict__ mb2) {
  int b = blockIdx.z;
  int c = blockIdx.y;
  int band = blockIdx.x;               // 0..7, 32 rows each
  int tid = threadIdx.x;
  int cs = tid & 31;                   // col segment: j0 = cs*8
  int rr = tid >> 5;                   // 0..7 -> r0 = band*32 + rr*4
  int j0 = cs * 8;
  int r0 = band * 32 + rr * 4;
  const unsigned short* base = mb + ((size_t)(b * 256 + c)) * NHW;
  unsigned short* obase = mb2 + ((size_t)(b * 256 + c)) * NHW;

  float w9[9];
#pragma unroll
  for (int t = 0; t < 9; t++) w9[t] = m2w[c * 9 + t];
  float bias = m2b[c];

  // load 6 input rows (r0-1 .. r0+4), 10 cols each (halo of 1 on both sides)
  float f[6][10];
#pragma unroll
  for (int rowi = 0; rowi < 6; rowi++) {
    int r = r0 - 1 + rowi;
    short8 v = {0, 0, 0, 0, 0, 0, 0, 0};
    unsigned short lft = 0, rgt = 0;
    if (r >= 0 && r < 256) {
      v = *(const short8*)(base + r * 256 + j0);      // 16B aligned
      if (j0 > 0)       lft = base[r * 256 + j0 - 1];
      if (j0 + 8 < 256) rgt = base[r * 256 + j0 + 8];
    }
    f[rowi][0] = bf2f(lft);
#pragma unroll
    for (int x = 0; x < 8; x++) f[rowi][1 + x] = bf2f((unsigned short)v[x]);
    f[rowi][9] = bf2f(rgt);
  }

#pragma unroll
  for (int ri = 0; ri < 4; ri++) {
    float acc[8];
#pragma unroll
    for (int jj = 0; jj < 8; jj++) acc[jj] = bias;
#pragma unroll
    for (int kh = 0; kh < 3; kh++) {
#pragma unroll
      for (int kw = 0; kw < 3; kw++) {
        float wv = w9[kh * 3 + kw];
#pragma unroll
        for (int jj = 0; jj < 8; jj++) acc[jj] += wv * f[ri + kh][jj + kw];
      }
    }
    short8 o;
#pragma unroll
    for (int jj = 0; jj < 8; jj++) o[jj] = (short)f2bf(geluf(acc[jj]));
    *(short8*)(obase + (r0 + ri) * 256 + j0) = o;
  }
}

// K8: out = attention + conv1x1(m2, 256->128) + m3_b ; bf16 in, fp32 in/out (d_out)
__global__ void __launch_bounds__(256) k8_m3(
    const unsigned short* __restrict__ mb2, const float* __restrict__ m3w,
    const float* __restrict__ m3b, float* __restrict__ out) {
  int n0 = blockIdx.x * 64;
  int og = blockIdx.y, b = blockIdx.z;
  int tid = threadIdx.x;
  int ot = tid >> 4, pt = tid & 15;
  __shared__ __align__(16) float aL[2048];
  __shared__ __align__(16) float wL[32 * 68];
  float acc[4][4];
#pragma unroll
  for (int x = 0; x < 4; x++)
#pragma unroll
    for (int y = 0; y < 4; y++) acc[x][y] = 0.f;
  for (int cc = 0; cc < 256; cc += 32) {
    __syncthreads();
#pragma unroll
    for (int k = 0; k < 2; k++) {
      int e4 = (k * 256 + tid) * 4;
      int ci = e4 >> 6, p0 = e4 & 63;
      const ushort4 uv = *(const ushort4*)(mb2 + ((size_t)(b * 256 + cc + ci)) * NHW + n0 + p0);
      aL[ci * 64 + p0 + 0] = bf2f(uv.x);
      aL[ci * 64 + p0 + 1] = bf2f(uv.y);
      aL[ci * 64 + p0 + 2] = bf2f(uv.z);
      aL[ci * 64 + p0 + 3] = bf2f(uv.w);
    }
#pragma unroll
    for (int k = 0; k < 8; k++) {
      int idx = k * 256 + tid;
      int o = idx >> 5, ci2 = idx & 31;
      wL[ci2 * 68 + o] = m3w[(og * 64 + o) * 256 + cc + ci2];
    }
    __syncthreads();
    for (int ci = 0; ci < 32; ci++) {
      float4 a4 = *(const float4*)(aL + ci * 64 + pt * 4);
      float4 w4 = *(const float4*)(wL + ci * 68 + ot * 4);
      acc[0][0] += w4.x * a4.x; acc[0][1] += w4.x * a4.y; acc[0][2] += w4.x * a4.z; acc[0][3] += w4.x * a4.w;
      acc[1][0] += w4.y * a4.x; acc[1][1] += w4.y * a4.y; acc[1][2] += w4.y * a4.z; acc[1][3] += w4.y * a4.w;
      acc[2][0] += w4.z * a4.x; acc[2][1] += w4.z * a4.y; acc[2][2] += w4.z * a4.z; acc[2][3] += w4.z * a4.w;
      acc[3][0] += w4.w * a4.x; acc[3][1] += w4.w * a4.y; acc[3][2] += w4.w * a4.z; acc[3][3] += w4.w * a4.w;
    }
  }
#pragma unroll
  for (int oi = 0; oi < 4; oi++) {
    int o = og * 64 + ot * 4 + oi;
    float bo = m3b[o];
    size_t addr = ((size_t)(b * 128 + o)) * NHW + n0 + pt * 4;
    float4 prev = *(const float4*)(out + addr);
    float4 res;
    res.x = prev.x + acc[oi][0] + bo;
    res.y = prev.y + acc[oi][1] + bo;
    res.z = prev.z + acc[oi][2] + bo;
    res.w = prev.w + acc[oi][3] + bo;
    *(float4*)(out + addr) = res;
  }
}

extern "C" void kernel_launch(void* const* d_in, const int* in_sizes, int n_in,
                              void* d_out, int out_size, void* d_ws, size_t ws_size,
                              hipStream_t stream) {
  const float* x1  = (const float*)d_in[0];
  const float* x2  = (const float*)d_in[1];
  const float* q1w = (const float*)d_in[2];  const float* q1b = (const float*)d_in[3];
  const float* q2w = (const float*)d_in[4];  const float* q2b = (const float*)d_in[5];
  const float* k1w = (const float*)d_in[6];  const float* k1b = (const float*)d_in[7];
  const float* k2w = (const float*)d_in[8];  const float* k2b = (const float*)d_in[9];
  const float* v1w = (const float*)d_in[10]; const float* v1b = (const float*)d_in[11];
  const float* v2w = (const float*)d_in[12]; const float* v2b = (const float*)d_in[13];
  const float* rw  = (const float*)d_in[14]; const float* rb  = (const float*)d_in[15];
  const float* m1w = (const float*)d_in[16]; const float* m1b = (const float*)d_in[17];
  const float* m2w = (const float*)d_in[18]; const float* m2b = (const float*)d_in[19];
  const float* m3w = (const float*)d_in[20]; const float* m3b = (const float*)d_in[21];
  float* ws = (float*)d_ws;
  float* out = (float*)d_out;
  unsigned short* mb  = (unsigned short*)d_ws;
  unsigned short* mb2 = (unsigned short*)d_ws + MB2_US;
  unsigned short* attB = (unsigned short*)(ws + OFF_ATT);
  unsigned short* wAu  = (unsigned short*)(ws + OFF_RWT);

  (void)hipMemsetAsync((char*)d_ws + OFF_CTX * sizeof(float), 0, (4096 + 256) * sizeof(float), stream);
  k0_wprep<<<800, 256, 0, stream>>>(rw, wAu);
  k1_qkv<<<1024, 256, 0, stream>>>(x1, x2, q1w, q1b, k1w, k1b, v1w, v1b, ws);
  k2_dw<<<32768, 256, 0, stream>>>(ws, k2w, k2b, k1b, v2w, v2b);
  k3_ctx<<<128, 256, 0, stream>>>(ws);
  k4_att<<<512, 256, 0, stream>>>(ws, q2w, q2b, q1b);
  k5_mfma<<<dim3(256, 2, 4), 256, 0, stream>>>(attB, wAu, rb, out);
  k6_m1<<<dim3(1024, 4, 4), 256, 0, stream>>>(out, m1w, m1b, mb);
  k7_m2<<<dim3(8, 256, 4), 256, 0, stream>>>(mb, m2w, m2b, mb2);
  k8_m3<<<dim3(1024, 2, 4), 256, 0, stream>>>(mb2, m3w, m3b, out);
}

// Round 2
// 1128.647 us; speedup vs baseline: 1.4458x; 1.1634x over previous
//
#include <hip/hip_runtime.h>
#include <hip/hip_bf16.h>
#include <cstdint>

#define NHW 65536
#define NSQ 32768

// workspace layout (float slots)
static constexpr size_t OFF_AQ  = 0;          // (4,64,256,128) conv1x1_q at nonanchor (squeezed)
static constexpr size_t OFF_AK  = 8388608;    // (4,64,256,128) conv1x1_k at anchor (squeezed)
static constexpr size_t OFF_AV  = 16777216;   // (4,64,256,256) conv1x1_v full res
static constexpr size_t OFF_EK  = 33554432;   // (4,64,256,128) exp(k_dw) squeezed
static constexpr size_t OFF_VD  = 41943040;   // (4,64,256,128) v_dw squeezed
static constexpr size_t OFF_ATT = 50331648;   // bf16 (4,256,128,64) att squeezed, channel-innermost
static constexpr size_t OFF_CTX = 58720256;   // 4*4*16*16
static constexpr size_t OFF_Z   = 58724352;   // 4*64
static constexpr size_t OFF_RWT = 58724608;   // bf16 wA[tap(25)][c/8(8)][o(128)][c%8(8)] = 204800 ushorts
static constexpr size_t MB2_US  = 67108864;   // ushort offset of mbuf2 (mbuf at 0) - phases don't overlap
// bf16 attention [b][pixel][o(128)] - lives only between k5 and k6 (region later clobbered by mb2)
static constexpr size_t A16_US  = 67108864;   // 33.55M ushorts
// bf16 packed m1 weights [chunk(16)][o(256)][8] - after wAu's ushort extent
static constexpr size_t W6_US   = 117654016;  // 32768 ushorts

typedef __attribute__((ext_vector_type(8))) short short8;
typedef __attribute__((ext_vector_type(4))) float floatx4;

// tap tables: first 13 = even parity (kh+kw even), last 12 = odd parity
__device__ __constant__ int TKH[25] = {0,0,0,1,1,2,2,2,3,3,4,4,4,  0,0,1,1,1,2,2,3,3,3,4,4};
__device__ __constant__ int TKW[25] = {0,2,4,1,3,0,2,4,1,3,0,2,4,  1,3,0,2,4,1,3,0,2,4,1,3};

__device__ __forceinline__ float geluf(float x) {
  return 0.5f * x * (1.0f + erff(x * 0.70710678118654752440f));
}
__device__ __forceinline__ unsigned short f2bf(float f) {
  union { float f; uint32_t u; } v; v.f = f;
  uint32_t x = v.u;
  uint32_t r = x + 0x7fffu + ((x >> 16) & 1u);
  return (unsigned short)(r >> 16);
}
__device__ __forceinline__ float bf2f(unsigned short u) {
  union { uint32_t i; float f; } v; v.i = ((uint32_t)u) << 16; return v.f;
}

// K0: prep conv5 weights into A-fragment order: wA[tap][c/8][o][c%8] bf16
__global__ void __launch_bounds__(256) k0_wprep(const float* __restrict__ rw,
                                                unsigned short* __restrict__ wAu) {
  int idx = blockIdx.x * 256 + threadIdx.x;   // 204800 total
  int cj = idx & 7, o = (idx >> 3) & 127, chunk = (idx >> 10) & 7, tap = idx >> 13;
  int c = chunk * 8 + cj;
  int t = TKH[tap] * 5 + TKW[tap];
  wAu[idx] = f2bf(rw[(o * 64 + c) * 25 + t]);
}

// K0b: pack m1 weights to bf16 B-fragment order: w6[chunk(16)][o(256)][cj(8)]
__global__ void __launch_bounds__(256) k0b_w6(const float* __restrict__ m1w,
                                              unsigned short* __restrict__ w6) {
  int idx = blockIdx.x * 256 + threadIdx.x;   // 32768 total
  int cj = idx & 7, o = (idx >> 3) & 255, chunk = idx >> 11;
  w6[idx] = f2bf(m1w[o * 128 + chunk * 8 + cj]);
}

// K1: 1x1 convs. q at nonanchor((i+j)%2==0), k at anchor, v everywhere.
__global__ void __launch_bounds__(256) k1_qkv(
    const float* __restrict__ x1, const float* __restrict__ x2,
    const float* __restrict__ q1w, const float* __restrict__ q1b,
    const float* __restrict__ k1w, const float* __restrict__ k1b,
    const float* __restrict__ v1w, const float* __restrict__ v1b,
    float* ws) {
  __shared__ float wq[4096], wk[4096], wv[4096];
  int tid = threadIdx.x;
  for (int idx = tid; idx < 4096; idx += 256) {
    int o = idx >> 6, c = idx & 63;        // coalesced global reads
    wq[c * 64 + o] = q1w[o * 64 + c];
    wk[c * 64 + o] = k1w[o * 64 + c];
    wv[c * 64 + o] = v1w[o * 64 + c];
  }
  __syncthreads();
  int b = blockIdx.x >> 8, i = blockIdx.x & 255;
  int w = tid >> 6, l = tid & 63;
  int j = (((w >> 1) * 64 + l) << 1) | (w & 1);  // wave-uniform column parity
  int par = (i + j) & 1;                          // 1 = anchor -> k
  const float* wsel = par ? wk : wq;
  const float* bsel = par ? k1b : q1b;
  float acc[64];
#pragma unroll
  for (int o = 0; o < 64; o++) acc[o] = bsel[o];
  const float* xp = x1 + ((size_t)b * 64) * NHW + i * 256 + j;
  for (int c = 0; c < 64; c++) {
    float v = xp[(size_t)c * NHW];
    const float* wr = wsel + c * 64;
#pragma unroll
    for (int o = 0; o < 64; o++) acc[o] += wr[o] * v;
  }
  {
    float* dst = ws + (par ? OFF_AK : OFF_AQ) + ((size_t)b * 64) * NSQ + i * 128 + (j >> 1);
#pragma unroll
    for (int o = 0; o < 64; o++) dst[(size_t)o * NSQ] = acc[o];
  }
#pragma unroll
  for (int o = 0; o < 64; o++) acc[o] = v1b[o];
  const float* xp2 = x2 + ((size_t)b * 64) * NHW + i * 256 + j;
  for (int c = 0; c < 64; c++) {
    float v = xp2[(size_t)c * NHW];
    const float* wr = wv + c * 64;
#pragma unroll
    for (int o = 0; o < 64; o++) acc[o] += wr[o] * v;
  }
  float* dv = ws + OFF_AV + ((size_t)b * 64) * NHW + i * 256 + j;
#pragma unroll
  for (int o = 0; o < 64; o++) dv[(size_t)o * NHW] = acc[o];
}

// K2: k depthwise (5 real taps + bias correction) -> exp; v depthwise (9 taps, full res);
// accumulate Z[b,c] = sum exp(kdw)
__global__ void __launch_bounds__(256) k2_dw(
    float* ws,
    const float* __restrict__ kw2, const float* __restrict__ kb2, const float* __restrict__ kb1,
    const float* __restrict__ vw2, const float* __restrict__ vb2) {
  int bid = blockIdx.x;                 // 4*64*128
  int b = bid >> 13, c = (bid >> 7) & 63, ip = bid & 127;
  int tid = threadIdx.x;
  int i = ip * 2 + (tid >> 7);
  int jp = tid & 127;
  int s = 1 - (i & 1);                  // anchor: col = 2*jp + s
  int j = 2 * jp + s;
  const float* AK = ws + OFF_AK + ((size_t)(b * 64 + c)) * NSQ;
  const float* w9 = kw2 + c * 9;
  float acc = kb2[c] + w9[4] * AK[i * 128 + jp];
  int cl = jp - 1 + s, cr = jp + s;
  if (i > 0) {
    const float* r = AK + (i - 1) * 128;
    if (cl >= 0)   acc += w9[0] * r[cl];
    if (cr <= 127) acc += w9[2] * r[cr];
  }
  if (i < 255) {
    const float* r = AK + (i + 1) * 128;
    if (cl >= 0)   acc += w9[6] * r[cl];
    if (cr <= 127) acc += w9[8] * r[cr];
  }
  float bs = 0.f;
  if (i > 0)   bs += w9[1];
  if (i < 255) bs += w9[7];
  if (j > 0)   bs += w9[3];
  if (j < 255) bs += w9[5];
  acc += kb1[c] * bs;                   // masked neighbors contribute conv1 bias only
  float ek = expf(acc);
  ws[OFF_EK + ((size_t)(b * 64 + c)) * NSQ + i * 128 + jp] = ek;

  const float* AV = ws + OFF_AV + ((size_t)(b * 64 + c)) * NHW;
  const float* vw = vw2 + c * 9;
  float av = vb2[c];
#pragma unroll
  for (int kh = 0; kh < 3; kh++) {
    int r = i - 1 + kh;
    if (r < 0 || r > 255) continue;
    const float* rp = AV + r * 256;
#pragma unroll
    for (int kwd = 0; kwd < 3; kwd++) {
      int u = j - 1 + kwd;
      if (u < 0 || u > 255) continue;
      av += vw[kh * 3 + kwd] * rp[u];
    }
  }
  ws[OFF_VD + ((size_t)(b * 64 + c)) * NSQ + i * 128 + jp] = av;

  __shared__ float red[256];
  red[tid] = ek;
  __syncthreads();
#pragma unroll
  for (int off = 128; off > 0; off >>= 1) {
    if (tid < off) red[tid] += red[tid + off];
    __syncthreads();
  }
  if (tid == 0) atomicAdd(ws + OFF_Z + (b * 64 + c), red[0]);
}

// K3: ctx_raw[b,h,d,e] = sum_n ek[b,h*16+d,n] * vdw[b,h*16+e,n]
__global__ void __launch_bounds__(256) k3_ctx(float* ws) {
  int bid = blockIdx.x;                 // 4*4*8
  int b = bid >> 5, h = (bid >> 3) & 3, ch = bid & 7;
  int n0 = ch * 4096;
  int tid = threadIdx.x;
  int d = tid >> 4, e = tid & 15;
  __shared__ float ekt[16][260];
  __shared__ float vdt[16][260];
  const float* ekb = ws + OFF_EK + ((size_t)(b * 64 + h * 16)) * NSQ + n0;
  const float* vdb = ws + OFF_VD + ((size_t)(b * 64 + h * 16)) * NSQ + n0;
  float acc = 0.f;
  for (int sub = 0; sub < 16; sub++) {
    __syncthreads();
#pragma unroll
    for (int r = 0; r < 16; r++) {
      ekt[r][tid] = ekb[(size_t)r * NSQ + sub * 256 + tid];
      vdt[r][tid] = vdb[(size_t)r * NSQ + sub * 256 + tid];
    }
    __syncthreads();
#pragma unroll 8
    for (int x = 0; x < 256; x++) acc += ekt[d][x] * vdt[e][x];
  }
  atomicAdd(ws + OFF_CTX + ((b * 4 + h) * 16 + d) * 16 + e, acc);
}

// K4: q depthwise + softmax over d, att[e] = sum_d (ctx_raw/Z)[d,e]*qsoft[d];
// store bf16, channel-innermost [b][i][jp][c]
__global__ void __launch_bounds__(256) k4_att(
    float* ws,
    const float* __restrict__ qw2, const float* __restrict__ qb2, const float* __restrict__ qb1) {
  int b = blockIdx.x >> 7, ip = blockIdx.x & 127;
  int tid = threadIdx.x;
  int i = ip * 2 + (tid >> 7);
  int jp = tid & 127;
  __shared__ float ctxn[1024];
  for (int idx = tid; idx < 1024; idx += 256)
    ctxn[idx] = ws[OFF_CTX + b * 1024 + idx] / ws[OFF_Z + b * 64 + (idx >> 4)];
  __syncthreads();
  int s = i & 1;                        // nonanchor: col = 2*jp + s
  int j = 2 * jp + s;
  int cl = jp - 1 + s, cr = jp + s;
  unsigned short* attB = (unsigned short*)(ws + OFF_ATT);
  unsigned short* dstp = attB + (((size_t)(b * 256 + i)) * 128 + jp) * 64;
  for (int h = 0; h < 4; h++) {
    float qv[16];
#pragma unroll
    for (int dc = 0; dc < 16; dc++) {
      int c = h * 16 + dc;
      const float* AQ = ws + OFF_AQ + ((size_t)(b * 64 + c)) * NSQ;
      const float* w9 = qw2 + c * 9;
      float acc = qb2[c] + w9[4] * AQ[i * 128 + jp];
      if (i > 0) {
        const float* r = AQ + (i - 1) * 128;
        if (cl >= 0)   acc += w9[0] * r[cl];
        if (cr <= 127) acc += w9[2] * r[cr];
      }
      if (i < 255) {
        const float* r = AQ + (i + 1) * 128;
        if (cl >= 0)   acc += w9[6] * r[cl];
        if (cr <= 127) acc += w9[8] * r[cr];
      }
      float bs = 0.f;
      if (i > 0)   bs += w9[1];
      if (i < 255) bs += w9[7];
      if (j > 0)   bs += w9[3];
      if (j < 255) bs += w9[5];
      qv[dc] = acc + qb1[c] * bs;
    }
    float mx = qv[0];
#pragma unroll
    for (int dc = 1; dc < 16; dc++) mx = fmaxf(mx, qv[dc]);
    float sum = 0.f;
#pragma unroll
    for (int dc = 0; dc < 16; dc++) { qv[dc] = expf(qv[dc] - mx); sum += qv[dc]; }
    float inv = 1.0f / sum;
#pragma unroll
    for (int e = 0; e < 16; e++) {
      float a = 0.f;
#pragma unroll
      for (int dc = 0; dc < 16; dc++) a += ctxn[h * 256 + dc * 16 + e] * qv[dc];
      dstp[h * 16 + e] = f2bf(a * inv);
    }
  }
}

// K5: 5x5 conv 64->128ch over checkerboard-sparse att, as bf16 MFMA implicit GEMM.
// Per (b, parity): C[o=128][n=128 px (4 rows x 32 jp)] = sum_{tap,c} W[o][tap,c]*Att[tap,c][n].
// attL layout [lr(8)][cb(3)][pos(16)][slot=chunk^(pos&7)][8ch] -> conflict-free b128 r/w.
// Epilogue also emits bf16 attention in [b][pixel][o(128)] layout for k6's MFMA.
__global__ void __launch_bounds__(256) k5_mfma(
    const unsigned short* __restrict__ attB, const unsigned short* __restrict__ wAu,
    const float* __restrict__ rb, float* __restrict__ out,
    unsigned short* __restrict__ a16) {
  int p = blockIdx.y, b = blockIdx.z;
  int i0 = (blockIdx.x >> 2) * 4;
  int jp0 = (blockIdx.x & 3) * 32;
  int tid = threadIdx.x;
  int wv = tid >> 6, lane = tid & 63;
  int mh = wv & 1, nh = wv >> 1;
  int l15 = lane & 15, quad = lane >> 4;

  __shared__ __align__(16) unsigned short attL[24576];  // 48KB: X16=((lr*3+cb)*16+pos)*8+slot
  __shared__ __align__(16) unsigned short wL[8192];     // 16KB: X16=(chalf*4+quad)*128+o

  // stage att tile (8 rows x 48 cols x 64 ch): 3072 16B units
  const unsigned short* attBase = attB + ((size_t)b * 256) * 128 * 64;
  for (int k = 0; k < 12; k++) {
    int u = k * 256 + tid;
    int chunk = u & 7;
    int pos = (u >> 3) & 15;
    int cbr = u >> 7;                  // lr*3+cb, 0..23
    int cb = cbr % 3, lr = cbr / 3;
    int r = i0 - 2 + lr;
    int jp = jp0 - 2 + cb * 16 + pos;
    short8 v = {0, 0, 0, 0, 0, 0, 0, 0};
    if (r >= 0 && r < 256 && jp >= 0 && jp < 128)
      v = *(const short8*)(attBase + (((size_t)r * 128) + jp) * 64 + chunk * 8);
    int slot = chunk ^ (pos & 7);
    *(short8*)(attL + (((size_t)cbr * 16 + pos) * 8 + slot) * 8) = v;
  }

  floatx4 acc[16];
#pragma unroll
  for (int x = 0; x < 16; x++) acc[x] = floatx4{0.f, 0.f, 0.f, 0.f};

  int riv[4], ci2[4];
#pragma unroll
  for (int nt = 0; nt < 4; nt++) {
    int ntg = nh * 4 + nt;
    riv[nt] = ntg >> 1;
    ci2[nt] = (ntg & 1) * 16 + l15 + 2;
  }

  int t0 = p ? 13 : 0;
  int ntaps = p ? 12 : 13;
  for (int tt = 0; tt < ntaps; tt++) {
    int tap = t0 + tt;
    int kh = TKH[tap], kw = TKW[tap];
    __syncthreads();
    {
      const short8* src = (const short8*)(wAu + (size_t)tap * 8192);
      short8* dst = (short8*)wL;
#pragma unroll
      for (int k = 0; k < 4; k++) dst[k * 256 + tid] = src[k * 256 + tid];
    }
    __syncthreads();
#pragma unroll
    for (int chalf = 0; chalf < 2; chalf++) {
      short8 a[4], bf[4];
#pragma unroll
      for (int mt = 0; mt < 4; mt++)
        a[mt] = *(const short8*)(wL + (((chalf * 4 + quad) * 128) + mh * 64 + mt * 16 + l15) * 8);
#pragma unroll
      for (int nt = 0; nt < 4; nt++) {
        int lr = riv[nt] + kh;
        int off = ((kw - 2) + ((p + riv[nt]) & 1) - ((riv[nt] + kh) & 1)) >> 1;
        int lc = ci2[nt] + off;
        int cb = lc >> 4, pos = lc & 15;
        int slot = (chalf * 4 + quad) ^ (pos & 7);
        bf[nt] = *(const short8*)(attL + ((((lr * 3 + cb) * 16 + pos) * 8) + slot) * 8);
      }
#pragma unroll
      for (int mt = 0; mt < 4; mt++)
#pragma unroll
        for (int nt = 0; nt < 4; nt++)
          acc[mt * 4 + nt] =
              __builtin_amdgcn_mfma_f32_16x16x32_bf16(a[mt], bf[nt], acc[mt * 4 + nt], 0, 0, 0);
    }
  }

  // epilogue: D row = o = mh*64+mt*16+quad*4+reg, col = n = lane&15 within n-tile
#pragma unroll
  for (int mt = 0; mt < 4; mt++) {
#pragma unroll
    for (int nt = 0; nt < 4; nt++) {
      int ntg = nh * 4 + nt;
      int i = i0 + (ntg >> 1);
      int jp = jp0 + (ntg & 1) * 16 + l15;
      int j = 2 * jp + ((p + i) & 1);
      floatx4 v = acc[mt * 4 + nt];
      int o0 = mh * 64 + mt * 16 + quad * 4;
      ushort4 u4;
      float r0 = v[0] + rb[o0 + 0];
      float r1 = v[1] + rb[o0 + 1];
      float r2 = v[2] + rb[o0 + 2];
      float r3 = v[3] + rb[o0 + 3];
      out[(((size_t)(b * 128 + o0 + 0)) * 256 + i) * 256 + j] = r0;
      out[(((size_t)(b * 128 + o0 + 1)) * 256 + i) * 256 + j] = r1;
      out[(((size_t)(b * 128 + o0 + 2)) * 256 + i) * 256 + j] = r2;
      out[(((size_t)(b * 128 + o0 + 3)) * 256 + i) * 256 + j] = r3;
      u4.x = f2bf(r0); u4.y = f2bf(r1); u4.z = f2bf(r2); u4.w = f2bf(r3);
      *(ushort4*)(a16 + ((size_t)b * 65536 + (size_t)i * 256 + j) * 128 + o0) = u4;
    }
  }
}

// K6: m1 = gelu(conv1x1 128->256) as bf16 MFMA GEMM.
// A = attention pixels (m=pixel, k=c) from a16 [n][c] staged in LDS (slot swizzle);
// B = packed m1 weights w6[chunk][o][8] read direct from global (L1-resident).
// D: row=pixel (4 consecutive per thread), col=o -> ushort4 gelu stores keep mb [c][n] layout.
__global__ void __launch_bounds__(256) k6_m1(
    const unsigned short* __restrict__ a16, const unsigned short* __restrict__ w6,
    const float* __restrict__ m1b, unsigned short* __restrict__ mb) {
  int px0 = blockIdx.x * 128;
  int og = blockIdx.y, b = blockIdx.z;
  int tid = threadIdx.x;
  int wv = tid >> 6, lane = tid & 63;
  int mh = wv & 1, nh = wv >> 1;
  int l15 = lane & 15, quad = lane >> 4;
  __shared__ __align__(16) unsigned short attL[16384];  // 32KB: [n(128)][slot(16)][8]

  const unsigned short* src = a16 + ((size_t)b * 65536 + px0) * 128;
#pragma unroll
  for (int k = 0; k < 8; k++) {
    int u = k * 256 + tid;
    int n = u >> 4, chunk = u & 15;
    short8 v = *(const short8*)(src + (size_t)n * 128 + chunk * 8);
    int slot = chunk ^ (n & 7);
    *(short8*)(attL + ((size_t)n * 16 + slot) * 8) = v;
  }
  __syncthreads();

  floatx4 acc[16];
#pragma unroll
  for (int x = 0; x < 16; x++) acc[x] = floatx4{0.f, 0.f, 0.f, 0.f};

#pragma unroll
  for (int step = 0; step < 4; step++) {
    int chunk = step * 4 + quad;
    short8 a[4], bw[4];
#pragma unroll
    for (int mt = 0; mt < 4; mt++) {
      int row = mh * 64 + mt * 16 + l15;
      int slot = chunk ^ (row & 7);
      a[mt] = *(const short8*)(attL + (row * 16 + slot) * 8);
    }
#pragma unroll
    for (int nt = 0; nt < 4; nt++) {
      int o = og * 128 + nh * 64 + nt * 16 + l15;
      bw[nt] = *(const short8*)(w6 + ((size_t)chunk * 256 + o) * 8);
    }
#pragma unroll
    for (int mt = 0; mt < 4; mt++)
#pragma unroll
      for (int nt = 0; nt < 4; nt++)
        acc[mt * 4 + nt] =
            __builtin_amdgcn_mfma_f32_16x16x32_bf16(a[mt], bw[nt], acc[mt * 4 + nt], 0, 0, 0);
  }

#pragma unroll
  for (int nt = 0; nt < 4; nt++) {
    int o = og * 128 + nh * 64 + nt * 16 + l15;
    float bo = m1b[o];
#pragma unroll
    for (int mt = 0; mt < 4; mt++) {
      int px = px0 + mh * 64 + mt * 16 + quad * 4;
      floatx4 v = acc[mt * 4 + nt];
      ushort4 u;
      u.x = f2bf(geluf(v[0] + bo));
      u.y = f2bf(geluf(v[1] + bo));
      u.z = f2bf(geluf(v[2] + bo));
      u.w = f2bf(geluf(v[3] + bo));
      *(ushort4*)(mb + ((size_t)(b * 256 + o)) * NHW + px) = u;
    }
  }
}

// K7: m2 = gelu(depthwise 3x3 on 256ch), bf16 -> bf16.
// Register-blocked: each thread owns a 4-row x 8-col patch; loads its 6 input
// rows as one short8 + 2 edge scalars each (vs 9 scalar loads/pixel before).
// Block covers 32 rows x 256 cols of one (b,c) plane; row re-read factor 1.5x.
__global__ void __launch_bounds__(256) k7_m2(
    const unsigned short* __restrict__ mb, const float* __restrict__ m2w,
    const float* __restrict__ m2b, unsigned short* __restrict__ mb2) {
  int b = blockIdx.z;
  int c = blockIdx.y;
  int band = blockIdx.x;               // 0..7, 32 rows each
  int tid = threadIdx.x;
  int cs = tid & 31;                   // col segment: j0 = cs*8
  int rr = tid >> 5;                   // 0..7 -> r0 = band*32 + rr*4
  int j0 = cs * 8;
  int r0 = band * 32 + rr * 4;
  const unsigned short* base = mb + ((size_t)(b * 256 + c)) * NHW;
  unsigned short* obase = mb2 + ((size_t)(b * 256 + c)) * NHW;

  float w9[9];
#pragma unroll
  for (int t = 0; t < 9; t++) w9[t] = m2w[c * 9 + t];
  float bias = m2b[c];

  // load 6 input rows (r0-1 .. r0+4), 10 cols each (halo of 1 on both sides)
  float f[6][10];
#pragma unroll
  for (int rowi = 0; rowi < 6; rowi++) {
    int r = r0 - 1 + rowi;
    short8 v = {0, 0, 0, 0, 0, 0, 0, 0};
    unsigned short lft = 0, rgt = 0;
    if (r >= 0 && r < 256) {
      v = *(const short8*)(base + r * 256 + j0);      // 16B aligned
      if (j0 > 0)       lft = base[r * 256 + j0 - 1];
      if (j0 + 8 < 256) rgt = base[r * 256 + j0 + 8];
    }
    f[rowi][0] = bf2f(lft);
#pragma unroll
    for (int x = 0; x < 8; x++) f[rowi][1 + x] = bf2f((unsigned short)v[x]);
    f[rowi][9] = bf2f(rgt);
  }

#pragma unroll
  for (int ri = 0; ri < 4; ri++) {
    float acc[8];
#pragma unroll
    for (int jj = 0; jj < 8; jj++) acc[jj] = bias;
#pragma unroll
    for (int kh = 0; kh < 3; kh++) {
#pragma unroll
      for (int kw = 0; kw < 3; kw++) {
        float wv = w9[kh * 3 + kw];
#pragma unroll
        for (int jj = 0; jj < 8; jj++) acc[jj] += wv * f[ri + kh][jj + kw];
      }
    }
    short8 o;
#pragma unroll
    for (int jj = 0; jj < 8; jj++) o[jj] = (short)f2bf(geluf(acc[jj]));
    *(short8*)(obase + (r0 + ri) * 256 + j0) = o;
  }
}

// K8: out = attention + conv1x1(m2, 256->128) + m3_b ; bf16 in, fp32 in/out (d_out)
__global__ void __launch_bounds__(256) k8_m3(
    const unsigned short* __restrict__ mb2, const float* __restrict__ m3w,
    const float* __restrict__ m3b, float* __restrict__ out) {
  int n0 = blockIdx.x * 64;
  int og = blockIdx.y, b = blockIdx.z;
  int tid = threadIdx.x;
  int ot = tid >> 4, pt = tid & 15;
  __shared__ __align__(16) float aL[2048];
  __shared__ __align__(16) float wL[32 * 68];
  float acc[4][4];
#pragma unroll
  for (int x = 0; x < 4; x++)
#pragma unroll
    for (int y = 0; y < 4; y++) acc[x][y] = 0.f;
  for (int cc = 0; cc < 256; cc += 32) {
    __syncthreads();
#pragma unroll
    for (int k = 0; k < 2; k++) {
      int e4 = (k * 256 + tid) * 4;
      int ci = e4 >> 6, p0 = e4 & 63;
      const ushort4 uv = *(const ushort4*)(mb2 + ((size_t)(b * 256 + cc + ci)) * NHW + n0 + p0);
      aL[ci * 64 + p0 + 0] = bf2f(uv.x);
      aL[ci * 64 + p0 + 1] = bf2f(uv.y);
      aL[ci * 64 + p0 + 2] = bf2f(uv.z);
      aL[ci * 64 + p0 + 3] = bf2f(uv.w);
    }
#pragma unroll
    for (int k = 0; k < 8; k++) {
      int idx = k * 256 + tid;
      int o = idx >> 5, ci2 = idx & 31;
      wL[ci2 * 68 + o] = m3w[(og * 64 + o) * 256 + cc + ci2];
    }
    __syncthreads();
    for (int ci = 0; ci < 32; ci++) {
      float4 a4 = *(const float4*)(aL + ci * 64 + pt * 4);
      float4 w4 = *(const float4*)(wL + ci * 68 + ot * 4);
      acc[0][0] += w4.x * a4.x; acc[0][1] += w4.x * a4.y; acc[0][2] += w4.x * a4.z; acc[0][3] += w4.x * a4.w;
      acc[1][0] += w4.y * a4.x; acc[1][1] += w4.y * a4.y; acc[1][2] += w4.y * a4.z; acc[1][3] += w4.y * a4.w;
      acc[2][0] += w4.z * a4.x; acc[2][1] += w4.z * a4.y; acc[2][2] += w4.z * a4.z; acc[2][3] += w4.z * a4.w;
      acc[3][0] += w4.w * a4.x; acc[3][1] += w4.w * a4.y; acc[3][2] += w4.w * a4.z; acc[3][3] += w4.w * a4.w;
    }
  }
#pragma unroll
  for (int oi = 0; oi < 4; oi++) {
    int o = og * 64 + ot * 4 + oi;
    float bo = m3b[o];
    size_t addr = ((size_t)(b * 128 + o)) * NHW + n0 + pt * 4;
    float4 prev = *(const float4*)(out + addr);
    float4 res;
    res.x = prev.x + acc[oi][0] + bo;
    res.y = prev.y + acc[oi][1] + bo;
    res.z = prev.z + acc[oi][2] + bo;
    res.w = prev.w + acc[oi][3] + bo;
    *(float4*)(out + addr) = res;
  }
}

extern "C" void kernel_launch(void* const* d_in, const int* in_sizes, int n_in,
                              void* d_out, int out_size, void* d_ws, size_t ws_size,
                              hipStream_t stream) {
  const float* x1  = (const float*)d_in[0];
  const float* x2  = (const float*)d_in[1];
  const float* q1w = (const float*)d_in[2];  const float* q1b = (const float*)d_in[3];
  const float* q2w = (const float*)d_in[4];  const float* q2b = (const float*)d_in[5];
  const float* k1w = (const float*)d_in[6];  const float* k1b = (const float*)d_in[7];
  const float* k2w = (const float*)d_in[8];  const float* k2b = (const float*)d_in[9];
  const float* v1w = (const float*)d_in[10]; const float* v1b = (const float*)d_in[11];
  const float* v2w = (const float*)d_in[12]; const float* v2b = (const float*)d_in[13];
  const float* rw  = (const float*)d_in[14]; const float* rb  = (const float*)d_in[15];
  const float* m1w = (const float*)d_in[16]; const float* m1b = (const float*)d_in[17];
  const float* m2w = (const float*)d_in[18]; const float* m2b = (const float*)d_in[19];
  const float* m3w = (const float*)d_in[20]; const float* m3b = (const float*)d_in[21];
  float* ws = (float*)d_ws;
  float* out = (float*)d_out;
  unsigned short* mb  = (unsigned short*)d_ws;
  unsigned short* mb2 = (unsigned short*)d_ws + MB2_US;
  unsigned short* a16 = (unsigned short*)d_ws + A16_US;
  unsigned short* w6  = (unsigned short*)d_ws + W6_US;
  unsigned short* attB = (unsigned short*)(ws + OFF_ATT);
  unsigned short* wAu  = (unsigned short*)(ws + OFF_RWT);

  (void)hipMemsetAsync((char*)d_ws + OFF_CTX * sizeof(float), 0, (4096 + 256) * sizeof(float), stream);
  k0_wprep<<<800, 256, 0, stream>>>(rw, wAu);
  k0b_w6<<<128, 256, 0, stream>>>(m1w, w6);
  k1_qkv<<<1024, 256, 0, stream>>>(x1, x2, q1w, q1b, k1w, k1b, v1w, v1b, ws);
  k2_dw<<<32768, 256, 0, stream>>>(ws, k2w, k2b, k1b, v2w, v2b);
  k3_ctx<<<128, 256, 0, stream>>>(ws);
  k4_att<<<512, 256, 0, stream>>>(ws, q2w, q2b, q1b);
  k5_mfma<<<dim3(256, 2, 4), 256, 0, stream>>>(attB, wAu, rb, out, a16);
  k6_m1<<<dim3(512, 2, 4), 256, 0, stream>>>(a16, w6, m1b, mb);
  k7_m2<<<dim3(8, 256, 4), 256, 0, stream>>>(mb, m2w, m2b, mb2);
  k8_m3<<<dim3(1024, 2, 4), 256, 0, stream>>>(mb2, m3w, m3b, out);
}

// Round 3
// 1091.420 us; speedup vs baseline: 1.4951x; 1.0341x over previous
//
#include <hip/hip_runtime.h>
#include <hip/hip_bf16.h>
#include <cstdint>

#define NHW 65536
#define NSQ 32768

// workspace layout (float slots)
static constexpr size_t OFF_AQ  = 0;          // (4,64,256,128) conv1x1_q at nonanchor (squeezed)
static constexpr size_t OFF_AK  = 8388608;    // (4,64,256,128) conv1x1_k at anchor (squeezed)
static constexpr size_t OFF_AV  = 16777216;   // (4,64,256,256) conv1x1_v full res
static constexpr size_t OFF_EK  = 33554432;   // (4,64,256,128) exp(k_dw) squeezed
static constexpr size_t OFF_VD  = 41943040;   // (4,64,256,128) v_dw squeezed
static constexpr size_t OFF_ATT = 50331648;   // bf16 (4,256,128,64) att squeezed, channel-innermost
static constexpr size_t OFF_CTX = 58720256;   // 4*4*16*16
static constexpr size_t OFF_Z   = 58724352;   // 4*64
static constexpr size_t OFF_RWT = 58724608;   // bf16 wA[tap(25)][c/8(8)][o(128)][c%8(8)] = 204800 ushorts
static constexpr size_t MB2_US  = 67108864;   // ushort offset of mb2 [px][c] (mb at 0) - phases don't overlap
// bf16 attention [b][pixel][o(128)] - lives only between k5 and k6 (region later clobbered by mb2)
static constexpr size_t A16_US  = 67108864;   // 33.55M ushorts
// bf16 packed m1 weights [chunk(16)][o(256)][8] - after wAu's ushort extent
static constexpr size_t W6_US   = 117654016;  // 32768 ushorts
// bf16 packed m3 weights [chunk(32)][o(128)][8] - at ushort 0 (dead mb region),
// written by k0c AFTER k7 (k7's mb2 write clobbers the W6 tail region).
static constexpr size_t W8_US   = 0;          // 32768 ushorts

typedef __attribute__((ext_vector_type(8))) short short8;
typedef __attribute__((ext_vector_type(4))) float floatx4;

// tap tables: first 13 = even parity (kh+kw even), last 12 = odd parity
__device__ __constant__ int TKH[25] = {0,0,0,1,1,2,2,2,3,3,4,4,4,  0,0,1,1,1,2,2,3,3,3,4,4};
__device__ __constant__ int TKW[25] = {0,2,4,1,3,0,2,4,1,3,0,2,4,  1,3,0,2,4,1,3,0,2,4,1,3};

__device__ __forceinline__ float geluf(float x) {
  return 0.5f * x * (1.0f + erff(x * 0.70710678118654752440f));
}
__device__ __forceinline__ unsigned short f2bf(float f) {
  union { float f; uint32_t u; } v; v.f = f;
  uint32_t x = v.u;
  uint32_t r = x + 0x7fffu + ((x >> 16) & 1u);
  return (unsigned short)(r >> 16);
}
__device__ __forceinline__ float bf2f(unsigned short u) {
  union { uint32_t i; float f; } v; v.i = ((uint32_t)u) << 16; return v.f;
}

// K0: prep conv5 weights into A-fragment order: wA[tap][c/8][o][c%8] bf16
__global__ void __launch_bounds__(256) k0_wprep(const float* __restrict__ rw,
                                                unsigned short* __restrict__ wAu) {
  int idx = blockIdx.x * 256 + threadIdx.x;   // 204800 total
  int cj = idx & 7, o = (idx >> 3) & 127, chunk = (idx >> 10) & 7, tap = idx >> 13;
  int c = chunk * 8 + cj;
  int t = TKH[tap] * 5 + TKW[tap];
  wAu[idx] = f2bf(rw[(o * 64 + c) * 25 + t]);
}

// K0b: pack m1 weights to bf16 fragment order: w6[chunk(16)][o(256)][cj(8)]
__global__ void __launch_bounds__(256) k0b_w6(const float* __restrict__ m1w,
                                              unsigned short* __restrict__ w6) {
  int idx = blockIdx.x * 256 + threadIdx.x;   // 32768 total
  int cj = idx & 7, o = (idx >> 3) & 255, chunk = idx >> 11;
  w6[idx] = f2bf(m1w[o * 128 + chunk * 8 + cj]);
}

// K0c: pack m3 weights to bf16 fragment order: w8[chunk(32)][o(128)][cj(8)]
__global__ void __launch_bounds__(256) k0c_w8(const float* __restrict__ m3w,
                                              unsigned short* __restrict__ w8) {
  int idx = blockIdx.x * 256 + threadIdx.x;   // 32768 total
  int cj = idx & 7, o = (idx >> 3) & 127, chunk = idx >> 10;
  w8[idx] = f2bf(m3w[o * 256 + chunk * 8 + cj]);
}

// K1: 1x1 convs. q at nonanchor((i+j)%2==0), k at anchor, v everywhere.
__global__ void __launch_bounds__(256) k1_qkv(
    const float* __restrict__ x1, const float* __restrict__ x2,
    const float* __restrict__ q1w, const float* __restrict__ q1b,
    const float* __restrict__ k1w, const float* __restrict__ k1b,
    const float* __restrict__ v1w, const float* __restrict__ v1b,
    float* ws) {
  __shared__ float wq[4096], wk[4096], wv[4096];
  int tid = threadIdx.x;
  for (int idx = tid; idx < 4096; idx += 256) {
    int o = idx >> 6, c = idx & 63;        // coalesced global reads
    wq[c * 64 + o] = q1w[o * 64 + c];
    wk[c * 64 + o] = k1w[o * 64 + c];
    wv[c * 64 + o] = v1w[o * 64 + c];
  }
  __syncthreads();
  int b = blockIdx.x >> 8, i = blockIdx.x & 255;
  int w = tid >> 6, l = tid & 63;
  int j = (((w >> 1) * 64 + l) << 1) | (w & 1);  // wave-uniform column parity
  int par = (i + j) & 1;                          // 1 = anchor -> k
  const float* wsel = par ? wk : wq;
  const float* bsel = par ? k1b : q1b;
  float acc[64];
#pragma unroll
  for (int o = 0; o < 64; o++) acc[o] = bsel[o];
  const float* xp = x1 + ((size_t)b * 64) * NHW + i * 256 + j;
  for (int c = 0; c < 64; c++) {
    float v = xp[(size_t)c * NHW];
    const float* wr = wsel + c * 64;
#pragma unroll
    for (int o = 0; o < 64; o++) acc[o] += wr[o] * v;
  }
  {
    float* dst = ws + (par ? OFF_AK : OFF_AQ) + ((size_t)b * 64) * NSQ + i * 128 + (j >> 1);
#pragma unroll
    for (int o = 0; o < 64; o++) dst[(size_t)o * NSQ] = acc[o];
  }
#pragma unroll
  for (int o = 0; o < 64; o++) acc[o] = v1b[o];
  const float* xp2 = x2 + ((size_t)b * 64) * NHW + i * 256 + j;
  for (int c = 0; c < 64; c++) {
    float v = xp2[(size_t)c * NHW];
    const float* wr = wv + c * 64;
#pragma unroll
    for (int o = 0; o < 64; o++) acc[o] += wr[o] * v;
  }
  float* dv = ws + OFF_AV + ((size_t)b * 64) * NHW + i * 256 + j;
#pragma unroll
  for (int o = 0; o < 64; o++) dv[(size_t)o * NHW] = acc[o];
}

// K2: k depthwise (5 real taps + bias correction) -> exp; v depthwise (9 taps, full res);
// accumulate Z[b,c] = sum exp(kdw)
__global__ void __launch_bounds__(256) k2_dw(
    float* ws,
    const float* __restrict__ kw2, const float* __restrict__ kb2, const float* __restrict__ kb1,
    const float* __restrict__ vw2, const float* __restrict__ vb2) {
  int bid = blockIdx.x;                 // 4*64*128
  int b = bid >> 13, c = (bid >> 7) & 63, ip = bid & 127;
  int tid = threadIdx.x;
  int i = ip * 2 + (tid >> 7);
  int jp = tid & 127;
  int s = 1 - (i & 1);                  // anchor: col = 2*jp + s
  int j = 2 * jp + s;
  const float* AK = ws + OFF_AK + ((size_t)(b * 64 + c)) * NSQ;
  const float* w9 = kw2 + c * 9;
  float acc = kb2[c] + w9[4] * AK[i * 128 + jp];
  int cl = jp - 1 + s, cr = jp + s;
  if (i > 0) {
    const float* r = AK + (i - 1) * 128;
    if (cl >= 0)   acc += w9[0] * r[cl];
    if (cr <= 127) acc += w9[2] * r[cr];
  }
  if (i < 255) {
    const float* r = AK + (i + 1) * 128;
    if (cl >= 0)   acc += w9[6] * r[cl];
    if (cr <= 127) acc += w9[8] * r[cr];
  }
  float bs = 0.f;
  if (i > 0)   bs += w9[1];
  if (i < 255) bs += w9[7];
  if (j > 0)   bs += w9[3];
  if (j < 255) bs += w9[5];
  acc += kb1[c] * bs;                   // masked neighbors contribute conv1 bias only
  float ek = expf(acc);
  ws[OFF_EK + ((size_t)(b * 64 + c)) * NSQ + i * 128 + jp] = ek;

  const float* AV = ws + OFF_AV + ((size_t)(b * 64 + c)) * NHW;
  const float* vw = vw2 + c * 9;
  float av = vb2[c];
#pragma unroll
  for (int kh = 0; kh < 3; kh++) {
    int r = i - 1 + kh;
    if (r < 0 || r > 255) continue;
    const float* rp = AV + r * 256;
#pragma unroll
    for (int kwd = 0; kwd < 3; kwd++) {
      int u = j - 1 + kwd;
      if (u < 0 || u > 255) continue;
      av += vw[kh * 3 + kwd] * rp[u];
    }
  }
  ws[OFF_VD + ((size_t)(b * 64 + c)) * NSQ + i * 128 + jp] = av;

  __shared__ float red[256];
  red[tid] = ek;
  __syncthreads();
#pragma unroll
  for (int off = 128; off > 0; off >>= 1) {
    if (tid < off) red[tid] += red[tid + off];
    __syncthreads();
  }
  if (tid == 0) atomicAdd(ws + OFF_Z + (b * 64 + c), red[0]);
}

// K3: ctx_raw[b,h,d,e] = sum_n ek[b,h*16+d,n] * vdw[b,h*16+e,n]
__global__ void __launch_bounds__(256) k3_ctx(float* ws) {
  int bid = blockIdx.x;                 // 4*4*8
  int b = bid >> 5, h = (bid >> 3) & 3, ch = bid & 7;
  int n0 = ch * 4096;
  int tid = threadIdx.x;
  int d = tid >> 4, e = tid & 15;
  __shared__ float ekt[16][260];
  __shared__ float vdt[16][260];
  const float* ekb = ws + OFF_EK + ((size_t)(b * 64 + h * 16)) * NSQ + n0;
  const float* vdb = ws + OFF_VD + ((size_t)(b * 64 + h * 16)) * NSQ + n0;
  float acc = 0.f;
  for (int sub = 0; sub < 16; sub++) {
    __syncthreads();
#pragma unroll
    for (int r = 0; r < 16; r++) {
      ekt[r][tid] = ekb[(size_t)r * NSQ + sub * 256 + tid];
      vdt[r][tid] = vdb[(size_t)r * NSQ + sub * 256 + tid];
    }
    __syncthreads();
#pragma unroll 8
    for (int x = 0; x < 256; x++) acc += ekt[d][x] * vdt[e][x];
  }
  atomicAdd(ws + OFF_CTX + ((b * 4 + h) * 16 + d) * 16 + e, acc);
}

// K4: q depthwise + softmax over d, att[e] = sum_d (ctx_raw/Z)[d,e]*qsoft[d];
// store bf16, channel-innermost [b][i][jp][c]
__global__ void __launch_bounds__(256) k4_att(
    float* ws,
    const float* __restrict__ qw2, const float* __restrict__ qb2, const float* __restrict__ qb1) {
  int b = blockIdx.x >> 7, ip = blockIdx.x & 127;
  int tid = threadIdx.x;
  int i = ip * 2 + (tid >> 7);
  int jp = tid & 127;
  __shared__ float ctxn[1024];
  for (int idx = tid; idx < 1024; idx += 256)
    ctxn[idx] = ws[OFF_CTX + b * 1024 + idx] / ws[OFF_Z + b * 64 + (idx >> 4)];
  __syncthreads();
  int s = i & 1;                        // nonanchor: col = 2*jp + s
  int j = 2 * jp + s;
  int cl = jp - 1 + s, cr = jp + s;
  unsigned short* attB = (unsigned short*)(ws + OFF_ATT);
  unsigned short* dstp = attB + (((size_t)(b * 256 + i)) * 128 + jp) * 64;
  for (int h = 0; h < 4; h++) {
    float qv[16];
#pragma unroll
    for (int dc = 0; dc < 16; dc++) {
      int c = h * 16 + dc;
      const float* AQ = ws + OFF_AQ + ((size_t)(b * 64 + c)) * NSQ;
      const float* w9 = qw2 + c * 9;
      float acc = qb2[c] + w9[4] * AQ[i * 128 + jp];
      if (i > 0) {
        const float* r = AQ + (i - 1) * 128;
        if (cl >= 0)   acc += w9[0] * r[cl];
        if (cr <= 127) acc += w9[2] * r[cr];
      }
      if (i < 255) {
        const float* r = AQ + (i + 1) * 128;
        if (cl >= 0)   acc += w9[6] * r[cl];
        if (cr <= 127) acc += w9[8] * r[cr];
      }
      float bs = 0.f;
      if (i > 0)   bs += w9[1];
      if (i < 255) bs += w9[7];
      if (j > 0)   bs += w9[3];
      if (j < 255) bs += w9[5];
      qv[dc] = acc + qb1[c] * bs;
    }
    float mx = qv[0];
#pragma unroll
    for (int dc = 1; dc < 16; dc++) mx = fmaxf(mx, qv[dc]);
    float sum = 0.f;
#pragma unroll
    for (int dc = 0; dc < 16; dc++) { qv[dc] = expf(qv[dc] - mx); sum += qv[dc]; }
    float inv = 1.0f / sum;
#pragma unroll
    for (int e = 0; e < 16; e++) {
      float a = 0.f;
#pragma unroll
      for (int dc = 0; dc < 16; dc++) a += ctxn[h * 256 + dc * 16 + e] * qv[dc];
      dstp[h * 16 + e] = f2bf(a * inv);
    }
  }
}

// K5: 5x5 conv 64->128ch over checkerboard-sparse att, as bf16 MFMA implicit GEMM.
// Per (b, parity): C[o=128][n=128 px (4 rows x 32 jp)] = sum_{tap,c} W[o][tap,c]*Att[tap,c][n].
// attL layout [lr(8)][cb(3)][pos(16)][slot=chunk^(pos&7)][8ch] -> conflict-free b128 r/w.
// Epilogue also emits bf16 attention in [b][pixel][o(128)] layout for k6's MFMA.
__global__ void __launch_bounds__(256) k5_mfma(
    const unsigned short* __restrict__ attB, const unsigned short* __restrict__ wAu,
    const float* __restrict__ rb, float* __restrict__ out,
    unsigned short* __restrict__ a16) {
  int p = blockIdx.y, b = blockIdx.z;
  int i0 = (blockIdx.x >> 2) * 4;
  int jp0 = (blockIdx.x & 3) * 32;
  int tid = threadIdx.x;
  int wv = tid >> 6, lane = tid & 63;
  int mh = wv & 1, nh = wv >> 1;
  int l15 = lane & 15, quad = lane >> 4;

  __shared__ __align__(16) unsigned short attL[24576];  // 48KB: X16=((lr*3+cb)*16+pos)*8+slot
  __shared__ __align__(16) unsigned short wL[8192];     // 16KB: X16=(chalf*4+quad)*128+o

  // stage att tile (8 rows x 48 cols x 64 ch): 3072 16B units
  const unsigned short* attBase = attB + ((size_t)b * 256) * 128 * 64;
  for (int k = 0; k < 12; k++) {
    int u = k * 256 + tid;
    int chunk = u & 7;
    int pos = (u >> 3) & 15;
    int cbr = u >> 7;                  // lr*3+cb, 0..23
    int cb = cbr % 3, lr = cbr / 3;
    int r = i0 - 2 + lr;
    int jp = jp0 - 2 + cb * 16 + pos;
    short8 v = {0, 0, 0, 0, 0, 0, 0, 0};
    if (r >= 0 && r < 256 && jp >= 0 && jp < 128)
      v = *(const short8*)(attBase + (((size_t)r * 128) + jp) * 64 + chunk * 8);
    int slot = chunk ^ (pos & 7);
    *(short8*)(attL + (((size_t)cbr * 16 + pos) * 8 + slot) * 8) = v;
  }

  floatx4 acc[16];
#pragma unroll
  for (int x = 0; x < 16; x++) acc[x] = floatx4{0.f, 0.f, 0.f, 0.f};

  int riv[4], ci2[4];
#pragma unroll
  for (int nt = 0; nt < 4; nt++) {
    int ntg = nh * 4 + nt;
    riv[nt] = ntg >> 1;
    ci2[nt] = (ntg & 1) * 16 + l15 + 2;
  }

  int t0 = p ? 13 : 0;
  int ntaps = p ? 12 : 13;
  for (int tt = 0; tt < ntaps; tt++) {
    int tap = t0 + tt;
    int kh = TKH[tap], kw = TKW[tap];
    __syncthreads();
    {
      const short8* src = (const short8*)(wAu + (size_t)tap * 8192);
      short8* dst = (short8*)wL;
#pragma unroll
      for (int k = 0; k < 4; k++) dst[k * 256 + tid] = src[k * 256 + tid];
    }
    __syncthreads();
#pragma unroll
    for (int chalf = 0; chalf < 2; chalf++) {
      short8 a[4], bf[4];
#pragma unroll
      for (int mt = 0; mt < 4; mt++)
        a[mt] = *(const short8*)(wL + (((chalf * 4 + quad) * 128) + mh * 64 + mt * 16 + l15) * 8);
#pragma unroll
      for (int nt = 0; nt < 4; nt++) {
        int lr = riv[nt] + kh;
        int off = ((kw - 2) + ((p + riv[nt]) & 1) - ((riv[nt] + kh) & 1)) >> 1;
        int lc = ci2[nt] + off;
        int cb = lc >> 4, pos = lc & 15;
        int slot = (chalf * 4 + quad) ^ (pos & 7);
        bf[nt] = *(const short8*)(attL + ((((lr * 3 + cb) * 16 + pos) * 8) + slot) * 8);
      }
#pragma unroll
      for (int mt = 0; mt < 4; mt++)
#pragma unroll
        for (int nt = 0; nt < 4; nt++)
          acc[mt * 4 + nt] =
              __builtin_amdgcn_mfma_f32_16x16x32_bf16(a[mt], bf[nt], acc[mt * 4 + nt], 0, 0, 0);
    }
  }

  // epilogue: D row = o = mh*64+mt*16+quad*4+reg, col = n = lane&15 within n-tile
#pragma unroll
  for (int mt = 0; mt < 4; mt++) {
#pragma unroll
    for (int nt = 0; nt < 4; nt++) {
      int ntg = nh * 4 + nt;
      int i = i0 + (ntg >> 1);
      int jp = jp0 + (ntg & 1) * 16 + l15;
      int j = 2 * jp + ((p + i) & 1);
      floatx4 v = acc[mt * 4 + nt];
      int o0 = mh * 64 + mt * 16 + quad * 4;
      ushort4 u4;
      float r0 = v[0] + rb[o0 + 0];
      float r1 = v[1] + rb[o0 + 1];
      float r2 = v[2] + rb[o0 + 2];
      float r3 = v[3] + rb[o0 + 3];
      out[(((size_t)(b * 128 + o0 + 0)) * 256 + i) * 256 + j] = r0;
      out[(((size_t)(b * 128 + o0 + 1)) * 256 + i) * 256 + j] = r1;
      out[(((size_t)(b * 128 + o0 + 2)) * 256 + i) * 256 + j] = r2;
      out[(((size_t)(b * 128 + o0 + 3)) * 256 + i) * 256 + j] = r3;
      u4.x = f2bf(r0); u4.y = f2bf(r1); u4.z = f2bf(r2); u4.w = f2bf(r3);
      *(ushort4*)(a16 + ((size_t)b * 65536 + (size_t)i * 256 + j) * 128 + o0) = u4;
    }
  }
}

// K6: m1 = gelu(conv1x1 128->256) as bf16 MFMA GEMM.
// A = packed weights w6 (m=o), B = attention pixels from a16 [px][c] staged in LDS
// (slot swizzle). D: row=o (4 consecutive per lane via regs), col=px ->
// ushort4-along-o stores into mb [px][o(256)] channel-innermost layout.
__global__ void __launch_bounds__(256) k6_m1(
    const unsigned short* __restrict__ a16, const unsigned short* __restrict__ w6,
    const float* __restrict__ m1b, unsigned short* __restrict__ mb) {
  int px0 = blockIdx.x * 128;
  int og = blockIdx.y, b = blockIdx.z;
  int tid = threadIdx.x;
  int wv = tid >> 6, lane = tid & 63;
  int mh = wv & 1, nh = wv >> 1;
  int l15 = lane & 15, quad = lane >> 4;
  __shared__ __align__(16) unsigned short attL[16384];  // 32KB: [n(128)][slot(16)][8]

  const unsigned short* src = a16 + ((size_t)b * 65536 + px0) * 128;
#pragma unroll
  for (int k = 0; k < 8; k++) {
    int u = k * 256 + tid;
    int n = u >> 4, chunk = u & 15;
    short8 v = *(const short8*)(src + (size_t)n * 128 + chunk * 8);
    int slot = chunk ^ (n & 7);
    *(short8*)(attL + ((size_t)n * 16 + slot) * 8) = v;
  }
  __syncthreads();

  floatx4 acc[16];
#pragma unroll
  for (int x = 0; x < 16; x++) acc[x] = floatx4{0.f, 0.f, 0.f, 0.f};

#pragma unroll
  for (int step = 0; step < 4; step++) {
    int chunk = step * 4 + quad;
    short8 aw[4], bp[4];
#pragma unroll
    for (int mt = 0; mt < 4; mt++) {
      int o = og * 128 + mh * 64 + mt * 16 + l15;
      aw[mt] = *(const short8*)(w6 + ((size_t)chunk * 256 + o) * 8);
    }
#pragma unroll
    for (int nt = 0; nt < 4; nt++) {
      int row = nh * 64 + nt * 16 + l15;
      int slot = chunk ^ (row & 7);
      bp[nt] = *(const short8*)(attL + (row * 16 + slot) * 8);
    }
#pragma unroll
    for (int mt = 0; mt < 4; mt++)
#pragma unroll
      for (int nt = 0; nt < 4; nt++)
        acc[mt * 4 + nt] =
            __builtin_amdgcn_mfma_f32_16x16x32_bf16(aw[mt], bp[nt], acc[mt * 4 + nt], 0, 0, 0);
  }

#pragma unroll
  for (int mt = 0; mt < 4; mt++) {
    int o0 = og * 128 + mh * 64 + mt * 16 + quad * 4;
    float4 bo = *(const float4*)(m1b + o0);
#pragma unroll
    for (int nt = 0; nt < 4; nt++) {
      int px = px0 + nh * 64 + nt * 16 + l15;
      floatx4 v = acc[mt * 4 + nt];
      ushort4 u;
      u.x = f2bf(geluf(v[0] + bo.x));
      u.y = f2bf(geluf(v[1] + bo.y));
      u.z = f2bf(geluf(v[2] + bo.z));
      u.w = f2bf(geluf(v[3] + bo.w));
      *(ushort4*)(mb + ((size_t)b * 65536 + px) * 256 + o0) = u;
    }
  }
}

// K7: m2 = gelu(depthwise 3x3 on 256ch), bf16 -> bf16, channel-innermost [px][c].
// Thread: 4 channels (ushort4) x 1 output row x 64-col sliding window.
// All global loads/stores are 512B-coalesced per wave (lanes cover 256 channels).
__global__ void __launch_bounds__(256) k7_m2(
    const unsigned short* __restrict__ mb, const float* __restrict__ m2w,
    const float* __restrict__ m2b, unsigned short* __restrict__ mb2) {
  int b = blockIdx.y;
  int i0 = (blockIdx.x >> 2) * 4;
  int jq = blockIdx.x & 3;
  int t = threadIdx.x;
  int l = t & 63, ri = t >> 6;
  int co = l * 4;
  int i = i0 + ri;                      // this thread's output row
  int j0 = jq * 64;
  const unsigned short* ibase = mb + ((size_t)b * 65536) * 256 + co;
  unsigned short* obase = mb2 + ((size_t)b * 65536) * 256 + co;

  float w[9][4], bias[4];
#pragma unroll
  for (int cc = 0; cc < 4; cc++) {
    bias[cc] = m2b[co + cc];
#pragma unroll
    for (int tap = 0; tap < 9; tap++) w[tap][cc] = m2w[(co + cc) * 9 + tap];
  }

  // window rows i-1, i, i+1 x cols (j-1, j, j+1) x 4 channels
  float wA[3][4], wB[3][4], wC[3][4];

#define K7_LOAD(dst, ir, jc)                                                        \
  do {                                                                              \
    if ((unsigned)(ir) < 256u && (unsigned)(jc) < 256u) {                           \
      ushort4 u_ = *(const ushort4*)(ibase + ((size_t)((ir) * 256 + (jc))) * 256);  \
      dst[0] = bf2f(u_.x); dst[1] = bf2f(u_.y);                                     \
      dst[2] = bf2f(u_.z); dst[3] = bf2f(u_.w);                                     \
    } else {                                                                        \
      dst[0] = 0.f; dst[1] = 0.f; dst[2] = 0.f; dst[3] = 0.f;                       \
    }                                                                               \
  } while (0)

#pragma unroll
  for (int r = 0; r < 3; r++) {
    K7_LOAD(wA[r], i - 1 + r, j0 - 1);
    K7_LOAD(wB[r], i - 1 + r, j0);
  }

  for (int j = j0; j < j0 + 64; j++) {
#pragma unroll
    for (int r = 0; r < 3; r++) K7_LOAD(wC[r], i - 1 + r, j + 1);
    float acc[4];
#pragma unroll
    for (int cc = 0; cc < 4; cc++) {
      acc[cc] = bias[cc]
        + w[0][cc] * wA[0][cc] + w[1][cc] * wB[0][cc] + w[2][cc] * wC[0][cc]
        + w[3][cc] * wA[1][cc] + w[4][cc] * wB[1][cc] + w[5][cc] * wC[1][cc]
        + w[6][cc] * wA[2][cc] + w[7][cc] * wB[2][cc] + w[8][cc] * wC[2][cc];
    }
    ushort4 u;
    u.x = f2bf(geluf(acc[0]));
    u.y = f2bf(geluf(acc[1]));
    u.z = f2bf(geluf(acc[2]));
    u.w = f2bf(geluf(acc[3]));
    *(ushort4*)(obase + ((size_t)(i * 256 + j)) * 256) = u;
#pragma unroll
    for (int r = 0; r < 3; r++) {
#pragma unroll
      for (int cc = 0; cc < 4; cc++) { wA[r][cc] = wB[r][cc]; wB[r][cc] = wC[r][cc]; }
    }
  }
#undef K7_LOAD
}

// K8: out += conv1x1(m2, 256->128) + m3_b as bf16 MFMA GEMM.
// A = packed weights w8 (m=o), B = m2 pixels from mb2 [px][c(256)] staged to LDS
// in two 128-c halves (slot swizzle). D: row=o, col=px -> fully-coalesced fp32 RMW
// (16 consecutive px per store instruction = 64B lines).
__global__ void __launch_bounds__(256) k8_m3(
    const unsigned short* __restrict__ mb2, const unsigned short* __restrict__ w8,
    const float* __restrict__ m3b, float* __restrict__ out) {
  int px0 = blockIdx.x * 128;
  int b = blockIdx.z;
  int tid = threadIdx.x;
  int wv = tid >> 6, lane = tid & 63;
  int mh = wv & 1, nh = wv >> 1;
  int l15 = lane & 15, quad = lane >> 4;
  __shared__ __align__(16) unsigned short attL[16384];  // 32KB: [n(128)][slot(16)][8]

  floatx4 acc[16];
#pragma unroll
  for (int x = 0; x < 16; x++) acc[x] = floatx4{0.f, 0.f, 0.f, 0.f};

  for (int kk = 0; kk < 2; kk++) {
    if (kk) __syncthreads();
    const unsigned short* src = mb2 + ((size_t)b * 65536 + px0) * 256 + kk * 128;
#pragma unroll
    for (int k = 0; k < 8; k++) {
      int u = k * 256 + tid;
      int n = u >> 4, ch = u & 15;
      short8 v = *(const short8*)(src + (size_t)n * 256 + ch * 8);
      int slot = ch ^ (n & 7);
      *(short8*)(attL + ((size_t)n * 16 + slot) * 8) = v;
    }
    __syncthreads();

#pragma unroll
    for (int step = 0; step < 4; step++) {
      int ch = step * 4 + quad;            // chunk within this 128-c half
      int chg = kk * 16 + ch;              // global chunk (of 32)
      short8 aw[4], bp[4];
#pragma unroll
      for (int mt = 0; mt < 4; mt++) {
        int o = mh * 64 + mt * 16 + l15;
        aw[mt] = *(const short8*)(w8 + ((size_t)chg * 128 + o) * 8);
      }
#pragma unroll
      for (int nt = 0; nt < 4; nt++) {
        int row = nh * 64 + nt * 16 + l15;
        int slot = ch ^ (row & 7);
        bp[nt] = *(const short8*)(attL + (row * 16 + slot) * 8);
      }
#pragma unroll
      for (int mt = 0; mt < 4; mt++)
#pragma unroll
        for (int nt = 0; nt < 4; nt++)
          acc[mt * 4 + nt] =
              __builtin_amdgcn_mfma_f32_16x16x32_bf16(aw[mt], bp[nt], acc[mt * 4 + nt], 0, 0, 0);
    }
  }

#pragma unroll
  for (int mt = 0; mt < 4; mt++) {
    int o0 = mh * 64 + mt * 16 + quad * 4;
    float4 bo = *(const float4*)(m3b + o0);
#pragma unroll
    for (int nt = 0; nt < 4; nt++) {
      int px = px0 + nh * 64 + nt * 16 + l15;
      floatx4 v = acc[mt * 4 + nt];
      size_t a0 = ((size_t)(b * 128 + o0 + 0)) * NHW + px;
      size_t a1 = ((size_t)(b * 128 + o0 + 1)) * NHW + px;
      size_t a2 = ((size_t)(b * 128 + o0 + 2)) * NHW + px;
      size_t a3 = ((size_t)(b * 128 + o0 + 3)) * NHW + px;
      out[a0] += v[0] + bo.x;
      out[a1] += v[1] + bo.y;
      out[a2] += v[2] + bo.z;
      out[a3] += v[3] + bo.w;
    }
  }
}

extern "C" void kernel_launch(void* const* d_in, const int* in_sizes, int n_in,
                              void* d_out, int out_size, void* d_ws, size_t ws_size,
                              hipStream_t stream) {
  const float* x1  = (const float*)d_in[0];
  const float* x2  = (const float*)d_in[1];
  const float* q1w = (const float*)d_in[2];  const float* q1b = (const float*)d_in[3];
  const float* q2w = (const float*)d_in[4];  const float* q2b = (const float*)d_in[5];
  const float* k1w = (const float*)d_in[6];  const float* k1b = (const float*)d_in[7];
  const float* k2w = (const float*)d_in[8];  const float* k2b = (const float*)d_in[9];
  const float* v1w = (const float*)d_in[10]; const float* v1b = (const float*)d_in[11];
  const float* v2w = (const float*)d_in[12]; const float* v2b = (const float*)d_in[13];
  const float* rw  = (const float*)d_in[14]; const float* rb  = (const float*)d_in[15];
  const float* m1w = (const float*)d_in[16]; const float* m1b = (const float*)d_in[17];
  const float* m2w = (const float*)d_in[18]; const float* m2b = (const float*)d_in[19];
  const float* m3w = (const float*)d_in[20]; const float* m3b = (const float*)d_in[21];
  float* ws = (float*)d_ws;
  float* out = (float*)d_out;
  unsigned short* mb  = (unsigned short*)d_ws;            // [px][o(256)] after k6
  unsigned short* mb2 = (unsigned short*)d_ws + MB2_US;   // [px][c(256)] after k7
  unsigned short* a16 = (unsigned short*)d_ws + A16_US;
  unsigned short* w6  = (unsigned short*)d_ws + W6_US;
  unsigned short* w8  = (unsigned short*)d_ws + W8_US;    // written after k7 (dead mb region)
  unsigned short* attB = (unsigned short*)(ws + OFF_ATT);
  unsigned short* wAu  = (unsigned short*)(ws + OFF_RWT);

  (void)hipMemsetAsync((char*)d_ws + OFF_CTX * sizeof(float), 0, (4096 + 256) * sizeof(float), stream);
  k0_wprep<<<800, 256, 0, stream>>>(rw, wAu);
  k0b_w6<<<128, 256, 0, stream>>>(m1w, w6);
  k1_qkv<<<1024, 256, 0, stream>>>(x1, x2, q1w, q1b, k1w, k1b, v1w, v1b, ws);
  k2_dw<<<32768, 256, 0, stream>>>(ws, k2w, k2b, k1b, v2w, v2b);
  k3_ctx<<<128, 256, 0, stream>>>(ws);
  k4_att<<<512, 256, 0, stream>>>(ws, q2w, q2b, q1b);
  k5_mfma<<<dim3(256, 2, 4), 256, 0, stream>>>(attB, wAu, rb, out, a16);
  k6_m1<<<dim3(512, 2, 4), 256, 0, stream>>>(a16, w6, m1b, mb);
  k7_m2<<<dim3(256, 4), 256, 0, stream>>>(mb, m2w, m2b, mb2);
  k0c_w8<<<128, 256, 0, stream>>>(m3w, w8);
  k8_m3<<<dim3(512, 1, 4), 256, 0, stream>>>(mb2, w8, m3b, out);
}

// Round 4
// 1004.332 us; speedup vs baseline: 1.6248x; 1.0867x over previous
//
#include <hip/hip_runtime.h>
#include <hip/hip_bf16.h>
#include <cstdint>

#define NHW 65536
#define NSQ 32768

// workspace layout (float slots)
static constexpr size_t OFF_AQ  = 0;          // (4,64,256,128) conv1x1_q at nonanchor (squeezed)
static constexpr size_t OFF_AK  = 8388608;    // (4,64,256,128) conv1x1_k at anchor (squeezed)
static constexpr size_t OFF_AV  = 16777216;   // (4,64,256,256) conv1x1_v full res
static constexpr size_t OFF_EK  = 33554432;   // (4,64,256,128) exp(k_dw) squeezed
static constexpr size_t OFF_VD  = 41943040;   // (4,64,256,128) v_dw squeezed
static constexpr size_t OFF_ATT = 50331648;   // bf16 (4,256,128,64) att squeezed, channel-innermost
static constexpr size_t OFF_CTX = 58720256;   // 4*4*16*16
static constexpr size_t OFF_Z   = 58724352;   // 4*64
static constexpr size_t OFF_RWT = 58724608;   // bf16 wA[tap(25)][c/8(8)][o(128)][c%8(8)] = 204800 ushorts
static constexpr size_t MB2_US  = 67108864;   // ushort offset of mb2 [px][c] (mb at 0) - phases don't overlap
// bf16 attention [b][pixel][o(128)] - lives only between k5 and k6 (region later clobbered by mb2)
static constexpr size_t A16_US  = 67108864;   // 33.55M ushorts
// bf16 packed m1 weights [chunk(16)][o(256)][8] - after wAu's ushort extent
static constexpr size_t W6_US   = 117654016;  // 32768 ushorts
// bf16 packed m3 weights [chunk(32)][o(128)][8] - at ushort 0 (dead mb region),
// written by k0c AFTER k7 (k7's mb2 write clobbers the W6 tail region).
static constexpr size_t W8_US   = 0;          // 32768 ushorts

typedef __attribute__((ext_vector_type(8))) short short8;
typedef __attribute__((ext_vector_type(4))) float floatx4;

// tap tables: first 13 = even parity (kh+kw even), last 12 = odd parity
__device__ __constant__ int TKH[25] = {0,0,0,1,1,2,2,2,3,3,4,4,4,  0,0,1,1,1,2,2,3,3,3,4,4};
__device__ __constant__ int TKW[25] = {0,2,4,1,3,0,2,4,1,3,0,2,4,  1,3,0,2,4,1,3,0,2,4,1,3};

__device__ __forceinline__ float geluf(float x) {
  return 0.5f * x * (1.0f + erff(x * 0.70710678118654752440f));
}
__device__ __forceinline__ unsigned short f2bf(float f) {
  union { float f; uint32_t u; } v; v.f = f;
  uint32_t x = v.u;
  uint32_t r = x + 0x7fffu + ((x >> 16) & 1u);
  return (unsigned short)(r >> 16);
}
__device__ __forceinline__ float bf2f(unsigned short u) {
  union { uint32_t i; float f; } v; v.i = ((uint32_t)u) << 16; return v.f;
}

// K0: prep conv5 weights into A-fragment order: wA[tap][c/8][o][c%8] bf16
__global__ void __launch_bounds__(256) k0_wprep(const float* __restrict__ rw,
                                                unsigned short* __restrict__ wAu) {
  int idx = blockIdx.x * 256 + threadIdx.x;   // 204800 total
  int cj = idx & 7, o = (idx >> 3) & 127, chunk = (idx >> 10) & 7, tap = idx >> 13;
  int c = chunk * 8 + cj;
  int t = TKH[tap] * 5 + TKW[tap];
  wAu[idx] = f2bf(rw[(o * 64 + c) * 25 + t]);
}

// K0b: pack m1 weights to bf16 fragment order: w6[chunk(16)][o(256)][cj(8)]
__global__ void __launch_bounds__(256) k0b_w6(const float* __restrict__ m1w,
                                              unsigned short* __restrict__ w6) {
  int idx = blockIdx.x * 256 + threadIdx.x;   // 32768 total
  int cj = idx & 7, o = (idx >> 3) & 255, chunk = idx >> 11;
  w6[idx] = f2bf(m1w[o * 128 + chunk * 8 + cj]);
}

// K0c: pack m3 weights to bf16 fragment order: w8[chunk(32)][o(128)][cj(8)]
__global__ void __launch_bounds__(256) k0c_w8(const float* __restrict__ m3w,
                                              unsigned short* __restrict__ w8) {
  int idx = blockIdx.x * 256 + threadIdx.x;   // 32768 total
  int cj = idx & 7, o = (idx >> 3) & 127, chunk = idx >> 10;
  w8[idx] = f2bf(m3w[o * 256 + chunk * 8 + cj]);
}

// K1: 1x1 convs. q at nonanchor((i+j)%2==0), k at anchor, v everywhere.
__global__ void __launch_bounds__(256) k1_qkv(
    const float* __restrict__ x1, const float* __restrict__ x2,
    const float* __restrict__ q1w, const float* __restrict__ q1b,
    const float* __restrict__ k1w, const float* __restrict__ k1b,
    const float* __restrict__ v1w, const float* __restrict__ v1b,
    float* ws) {
  __shared__ float wq[4096], wk[4096], wv[4096];
  int tid = threadIdx.x;
  for (int idx = tid; idx < 4096; idx += 256) {
    int o = idx >> 6, c = idx & 63;        // coalesced global reads
    wq[c * 64 + o] = q1w[o * 64 + c];
    wk[c * 64 + o] = k1w[o * 64 + c];
    wv[c * 64 + o] = v1w[o * 64 + c];
  }
  __syncthreads();
  int b = blockIdx.x >> 8, i = blockIdx.x & 255;
  int w = tid >> 6, l = tid & 63;
  int j = (((w >> 1) * 64 + l) << 1) | (w & 1);  // wave-uniform column parity
  int par = (i + j) & 1;                          // 1 = anchor -> k
  const float* wsel = par ? wk : wq;
  const float* bsel = par ? k1b : q1b;
  float acc[64];
#pragma unroll
  for (int o = 0; o < 64; o++) acc[o] = bsel[o];
  const float* xp = x1 + ((size_t)b * 64) * NHW + i * 256 + j;
  for (int c = 0; c < 64; c++) {
    float v = xp[(size_t)c * NHW];
    const float* wr = wsel + c * 64;
#pragma unroll
    for (int o = 0; o < 64; o++) acc[o] += wr[o] * v;
  }
  {
    float* dst = ws + (par ? OFF_AK : OFF_AQ) + ((size_t)b * 64) * NSQ + i * 128 + (j >> 1);
#pragma unroll
    for (int o = 0; o < 64; o++) dst[(size_t)o * NSQ] = acc[o];
  }
#pragma unroll
  for (int o = 0; o < 64; o++) acc[o] = v1b[o];
  const float* xp2 = x2 + ((size_t)b * 64) * NHW + i * 256 + j;
  for (int c = 0; c < 64; c++) {
    float v = xp2[(size_t)c * NHW];
    const float* wr = wv + c * 64;
#pragma unroll
    for (int o = 0; o < 64; o++) acc[o] += wr[o] * v;
  }
  float* dv = ws + OFF_AV + ((size_t)b * 64) * NHW + i * 256 + j;
#pragma unroll
  for (int o = 0; o < 64; o++) dv[(size_t)o * NHW] = acc[o];
}

// K2: k depthwise (5 real taps + bias correction) -> exp; v depthwise (9 taps, full res);
// accumulate Z[b,c] = sum exp(kdw).
// Band-tiled: block stages 18 rows of AK (squeezed, 128 cols) and AV (full, 256 cols)
// into LDS with zero-padded halo cols/rows (branchless taps). Thread computes 8
// consecutive jp outputs; float4 stores; one atomicAdd per block.
__global__ void __launch_bounds__(256) k2_dw(
    float* ws,
    const float* __restrict__ kw2, const float* __restrict__ kb2, const float* __restrict__ kb1,
    const float* __restrict__ vw2, const float* __restrict__ vb2) {
  int ig = blockIdx.x, c = blockIdx.y, b = blockIdx.z;
  int i0 = ig * 16;
  int tid = threadIdx.x;

  __shared__ float akL[18][130];   // col k at index k+1; pads at 0 and 129
  __shared__ float avL[18][260];   // col j at index j+1; pads at 0 and 257
  __shared__ float red[256];

  const float* AKg = ws + OFF_AK + ((size_t)(b * 64 + c)) * NSQ;
  const float* AVg = ws + OFF_AV + ((size_t)(b * 64 + c)) * NHW;

  for (int idx = tid; idx < 18 * 128; idx += 256) {
    int r = idx >> 7, col = idx & 127;
    int gi = i0 - 1 + r;
    akL[r][1 + col] = (gi >= 0 && gi < 256) ? AKg[gi * 128 + col] : 0.f;
  }
  for (int idx = tid; idx < 18 * 256; idx += 256) {
    int r = idx >> 8, col = idx & 255;
    int gi = i0 - 1 + r;
    avL[r][1 + col] = (gi >= 0 && gi < 256) ? AVg[gi * 256 + col] : 0.f;
  }
  if (tid < 18) {
    akL[tid][0] = 0.f; akL[tid][129] = 0.f;
    avL[tid][0] = 0.f; avL[tid][257] = 0.f;
  }
  __syncthreads();

  int tr = tid >> 4, tj = tid & 15;
  int i = i0 + tr;
  int jp0 = tj * 8;
  int li = tr + 1;
  int s = 1 - (i & 1);                  // anchor: col = 2*jp + s

  const float* w9 = kw2 + c * 9;
  float kw0 = w9[0], kw1 = w9[1], kw2c = w9[2], kw3 = w9[3], kw4 = w9[4],
        kw5 = w9[5], kw6 = w9[6], kw7 = w9[7], kw8 = w9[8];
  float kb2c = kb2[c], kb1c = kb1[c];
  const float* vwp = vw2 + c * 9;
  float vw0 = vwp[0], vw1 = vwp[1], vw2v = vwp[2], vw3 = vwp[3], vw4 = vwp[4],
        vw5 = vwp[5], vw6 = vwp[6], vw7 = vwp[7], vw8 = vwp[8];
  float vbc = vb2[c];

  float ek[8], vd[8];
  float zsum = 0.f;
#pragma unroll
  for (int u = 0; u < 8; u++) {
    int jp = jp0 + u;
    int j = 2 * jp + s;
    float bs = 0.f;
    if (i > 0)   bs += kw1;
    if (i < 255) bs += kw7;
    if (j > 0)   bs += kw3;
    if (j < 255) bs += kw5;
    // K-path: masked taps read zero-pads -> identical to original skip semantics
    float acc = kb2c + kb1c * bs
      + kw4 * akL[li][1 + jp]
      + kw0 * akL[li - 1][jp + s] + kw2c * akL[li - 1][1 + jp + s]
      + kw6 * akL[li + 1][jp + s] + kw8 * akL[li + 1][1 + jp + s];
    float e = expf(acc);
    ek[u] = e; zsum += e;
    // V-path: 9 taps, full-res cols j-1..j+1 at LDS index j..j+2
    vd[u] = vbc
      + vw0 * avL[li - 1][j] + vw1 * avL[li - 1][1 + j] + vw2v * avL[li - 1][2 + j]
      + vw3 * avL[li    ][j] + vw4 * avL[li    ][1 + j] + vw5  * avL[li    ][2 + j]
      + vw6 * avL[li + 1][j] + vw7 * avL[li + 1][1 + j] + vw8  * avL[li + 1][2 + j];
  }

  float* ekp = ws + OFF_EK + ((size_t)(b * 64 + c)) * NSQ + i * 128 + jp0;
  float* vdp = ws + OFF_VD + ((size_t)(b * 64 + c)) * NSQ + i * 128 + jp0;
  float4 e0 = {ek[0], ek[1], ek[2], ek[3]}, e1 = {ek[4], ek[5], ek[6], ek[7]};
  float4 v0 = {vd[0], vd[1], vd[2], vd[3]}, v1 = {vd[4], vd[5], vd[6], vd[7]};
  *(float4*)(ekp) = e0; *(float4*)(ekp + 4) = e1;
  *(float4*)(vdp) = v0; *(float4*)(vdp + 4) = v1;

  red[tid] = zsum;
  __syncthreads();
#pragma unroll
  for (int off = 128; off > 0; off >>= 1) {
    if (tid < off) red[tid] += red[tid + off];
    __syncthreads();
  }
  if (tid == 0) atomicAdd(ws + OFF_Z + (b * 64 + c), red[0]);
}

// K3: ctx_raw[b,h,d,e] = sum_n ek[b,h*16+d,n] * vdw[b,h*16+e,n]
__global__ void __launch_bounds__(256) k3_ctx(float* ws) {
  int bid = blockIdx.x;                 // 4*4*8
  int b = bid >> 5, h = (bid >> 3) & 3, ch = bid & 7;
  int n0 = ch * 4096;
  int tid = threadIdx.x;
  int d = tid >> 4, e = tid & 15;
  __shared__ float ekt[16][260];
  __shared__ float vdt[16][260];
  const float* ekb = ws + OFF_EK + ((size_t)(b * 64 + h * 16)) * NSQ + n0;
  const float* vdb = ws + OFF_VD + ((size_t)(b * 64 + h * 16)) * NSQ + n0;
  float acc = 0.f;
  for (int sub = 0; sub < 16; sub++) {
    __syncthreads();
#pragma unroll
    for (int r = 0; r < 16; r++) {
      ekt[r][tid] = ekb[(size_t)r * NSQ + sub * 256 + tid];
      vdt[r][tid] = vdb[(size_t)r * NSQ + sub * 256 + tid];
    }
    __syncthreads();
#pragma unroll 8
    for (int x = 0; x < 256; x++) acc += ekt[d][x] * vdt[e][x];
  }
  atomicAdd(ws + OFF_CTX + ((b * 4 + h) * 16 + d) * 16 + e, acc);
}

// K4: q depthwise + softmax over d, att[e] = sum_d (ctx_raw/Z)[d,e]*qsoft[d];
// store bf16, channel-innermost [b][i][jp][c]
__global__ void __launch_bounds__(256) k4_att(
    float* ws,
    const float* __restrict__ qw2, const float* __restrict__ qb2, const float* __restrict__ qb1) {
  int b = blockIdx.x >> 7, ip = blockIdx.x & 127;
  int tid = threadIdx.x;
  int i = ip * 2 + (tid >> 7);
  int jp = tid & 127;
  __shared__ float ctxn[1024];
  for (int idx = tid; idx < 1024; idx += 256)
    ctxn[idx] = ws[OFF_CTX + b * 1024 + idx] / ws[OFF_Z + b * 64 + (idx >> 4)];
  __syncthreads();
  int s = i & 1;                        // nonanchor: col = 2*jp + s
  int j = 2 * jp + s;
  int cl = jp - 1 + s, cr = jp + s;
  unsigned short* attB = (unsigned short*)(ws + OFF_ATT);
  unsigned short* dstp = attB + (((size_t)(b * 256 + i)) * 128 + jp) * 64;
  for (int h = 0; h < 4; h++) {
    float qv[16];
#pragma unroll
    for (int dc = 0; dc < 16; dc++) {
      int c = h * 16 + dc;
      const float* AQ = ws + OFF_AQ + ((size_t)(b * 64 + c)) * NSQ;
      const float* w9 = qw2 + c * 9;
      float acc = qb2[c] + w9[4] * AQ[i * 128 + jp];
      if (i > 0) {
        const float* r = AQ + (i - 1) * 128;
        if (cl >= 0)   acc += w9[0] * r[cl];
        if (cr <= 127) acc += w9[2] * r[cr];
      }
      if (i < 255) {
        const float* r = AQ + (i + 1) * 128;
        if (cl >= 0)   acc += w9[6] * r[cl];
        if (cr <= 127) acc += w9[8] * r[cr];
      }
      float bs = 0.f;
      if (i > 0)   bs += w9[1];
      if (i < 255) bs += w9[7];
      if (j > 0)   bs += w9[3];
      if (j < 255) bs += w9[5];
      qv[dc] = acc + qb1[c] * bs;
    }
    float mx = qv[0];
#pragma unroll
    for (int dc = 1; dc < 16; dc++) mx = fmaxf(mx, qv[dc]);
    float sum = 0.f;
#pragma unroll
    for (int dc = 0; dc < 16; dc++) { qv[dc] = expf(qv[dc] - mx); sum += qv[dc]; }
    float inv = 1.0f / sum;
#pragma unroll
    for (int e = 0; e < 16; e++) {
      float a = 0.f;
#pragma unroll
      for (int dc = 0; dc < 16; dc++) a += ctxn[h * 256 + dc * 16 + e] * qv[dc];
      dstp[h * 16 + e] = f2bf(a * inv);
    }
  }
}

// K5: 5x5 conv 64->128ch over checkerboard-sparse att, as bf16 MFMA implicit GEMM.
// Per (b, parity): C[o=128][n=128 px (4 rows x 32 jp)] = sum_{tap,c} W[o][tap,c]*Att[tap,c][n].
// attL layout [lr(8)][cb(3)][pos(16)][slot=chunk^(pos&7)][8ch] -> conflict-free b128 r/w.
// Epilogue also emits bf16 attention in [b][pixel][o(128)] layout for k6's MFMA.
__global__ void __launch_bounds__(256) k5_mfma(
    const unsigned short* __restrict__ attB, const unsigned short* __restrict__ wAu,
    const float* __restrict__ rb, float* __restrict__ out,
    unsigned short* __restrict__ a16) {
  int p = blockIdx.y, b = blockIdx.z;
  int i0 = (blockIdx.x >> 2) * 4;
  int jp0 = (blockIdx.x & 3) * 32;
  int tid = threadIdx.x;
  int wv = tid >> 6, lane = tid & 63;
  int mh = wv & 1, nh = wv >> 1;
  int l15 = lane & 15, quad = lane >> 4;

  __shared__ __align__(16) unsigned short attL[24576];  // 48KB: X16=((lr*3+cb)*16+pos)*8+slot
  __shared__ __align__(16) unsigned short wL[8192];     // 16KB: X16=(chalf*4+quad)*128+o

  // stage att tile (8 rows x 48 cols x 64 ch): 3072 16B units
  const unsigned short* attBase = attB + ((size_t)b * 256) * 128 * 64;
  for (int k = 0; k < 12; k++) {
    int u = k * 256 + tid;
    int chunk = u & 7;
    int pos = (u >> 3) & 15;
    int cbr = u >> 7;                  // lr*3+cb, 0..23
    int cb = cbr % 3, lr = cbr / 3;
    int r = i0 - 2 + lr;
    int jp = jp0 - 2 + cb * 16 + pos;
    short8 v = {0, 0, 0, 0, 0, 0, 0, 0};
    if (r >= 0 && r < 256 && jp >= 0 && jp < 128)
      v = *(const short8*)(attBase + (((size_t)r * 128) + jp) * 64 + chunk * 8);
    int slot = chunk ^ (pos & 7);
    *(short8*)(attL + (((size_t)cbr * 16 + pos) * 8 + slot) * 8) = v;
  }

  floatx4 acc[16];
#pragma unroll
  for (int x = 0; x < 16; x++) acc[x] = floatx4{0.f, 0.f, 0.f, 0.f};

  int riv[4], ci2[4];
#pragma unroll
  for (int nt = 0; nt < 4; nt++) {
    int ntg = nh * 4 + nt;
    riv[nt] = ntg >> 1;
    ci2[nt] = (ntg & 1) * 16 + l15 + 2;
  }

  int t0 = p ? 13 : 0;
  int ntaps = p ? 12 : 13;
  for (int tt = 0; tt < ntaps; tt++) {
    int tap = t0 + tt;
    int kh = TKH[tap], kw = TKW[tap];
    __syncthreads();
    {
      const short8* src = (const short8*)(wAu + (size_t)tap * 8192);
      short8* dst = (short8*)wL;
#pragma unroll
      for (int k = 0; k < 4; k++) dst[k * 256 + tid] = src[k * 256 + tid];
    }
    __syncthreads();
#pragma unroll
    for (int chalf = 0; chalf < 2; chalf++) {
      short8 a[4], bf[4];
#pragma unroll
      for (int mt = 0; mt < 4; mt++)
        a[mt] = *(const short8*)(wL + (((chalf * 4 + quad) * 128) + mh * 64 + mt * 16 + l15) * 8);
#pragma unroll
      for (int nt = 0; nt < 4; nt++) {
        int lr = riv[nt] + kh;
        int off = ((kw - 2) + ((p + riv[nt]) & 1) - ((riv[nt] + kh) & 1)) >> 1;
        int lc = ci2[nt] + off;
        int cb = lc >> 4, pos = lc & 15;
        int slot = (chalf * 4 + quad) ^ (pos & 7);
        bf[nt] = *(const short8*)(attL + ((((lr * 3 + cb) * 16 + pos) * 8) + slot) * 8);
      }
#pragma unroll
      for (int mt = 0; mt < 4; mt++)
#pragma unroll
        for (int nt = 0; nt < 4; nt++)
          acc[mt * 4 + nt] =
              __builtin_amdgcn_mfma_f32_16x16x32_bf16(a[mt], bf[nt], acc[mt * 4 + nt], 0, 0, 0);
    }
  }

  // epilogue: D row = o = mh*64+mt*16+quad*4+reg, col = n = lane&15 within n-tile
#pragma unroll
  for (int mt = 0; mt < 4; mt++) {
#pragma unroll
    for (int nt = 0; nt < 4; nt++) {
      int ntg = nh * 4 + nt;
      int i = i0 + (ntg >> 1);
      int jp = jp0 + (ntg & 1) * 16 + l15;
      int j = 2 * jp + ((p + i) & 1);
      floatx4 v = acc[mt * 4 + nt];
      int o0 = mh * 64 + mt * 16 + quad * 4;
      ushort4 u4;
      float r0 = v[0] + rb[o0 + 0];
      float r1 = v[1] + rb[o0 + 1];
      float r2 = v[2] + rb[o0 + 2];
      float r3 = v[3] + rb[o0 + 3];
      out[(((size_t)(b * 128 + o0 + 0)) * 256 + i) * 256 + j] = r0;
      out[(((size_t)(b * 128 + o0 + 1)) * 256 + i) * 256 + j] = r1;
      out[(((size_t)(b * 128 + o0 + 2)) * 256 + i) * 256 + j] = r2;
      out[(((size_t)(b * 128 + o0 + 3)) * 256 + i) * 256 + j] = r3;
      u4.x = f2bf(r0); u4.y = f2bf(r1); u4.z = f2bf(r2); u4.w = f2bf(r3);
      *(ushort4*)(a16 + ((size_t)b * 65536 + (size_t)i * 256 + j) * 128 + o0) = u4;
    }
  }
}

// K6: m1 = gelu(conv1x1 128->256) as bf16 MFMA GEMM.
// A = packed weights w6 (m=o), B = attention pixels from a16 [px][c] staged in LDS
// (slot swizzle). D: row=o (4 consecutive per lane via regs), col=px ->
// ushort4-along-o stores into mb [px][o(256)] channel-innermost layout.
__global__ void __launch_bounds__(256) k6_m1(
    const unsigned short* __restrict__ a16, const unsigned short* __restrict__ w6,
    const float* __restrict__ m1b, unsigned short* __restrict__ mb) {
  int px0 = blockIdx.x * 128;
  int og = blockIdx.y, b = blockIdx.z;
  int tid = threadIdx.x;
  int wv = tid >> 6, lane = tid & 63;
  int mh = wv & 1, nh = wv >> 1;
  int l15 = lane & 15, quad = lane >> 4;
  __shared__ __align__(16) unsigned short attL[16384];  // 32KB: [n(128)][slot(16)][8]

  const unsigned short* src = a16 + ((size_t)b * 65536 + px0) * 128;
#pragma unroll
  for (int k = 0; k < 8; k++) {
    int u = k * 256 + tid;
    int n = u >> 4, chunk = u & 15;
    short8 v = *(const short8*)(src + (size_t)n * 128 + chunk * 8);
    int slot = chunk ^ (n & 7);
    *(short8*)(attL + ((size_t)n * 16 + slot) * 8) = v;
  }
  __syncthreads();

  floatx4 acc[16];
#pragma unroll
  for (int x = 0; x < 16; x++) acc[x] = floatx4{0.f, 0.f, 0.f, 0.f};

#pragma unroll
  for (int step = 0; step < 4; step++) {
    int chunk = step * 4 + quad;
    short8 aw[4], bp[4];
#pragma unroll
    for (int mt = 0; mt < 4; mt++) {
      int o = og * 128 + mh * 64 + mt * 16 + l15;
      aw[mt] = *(const short8*)(w6 + ((size_t)chunk * 256 + o) * 8);
    }
#pragma unroll
    for (int nt = 0; nt < 4; nt++) {
      int row = nh * 64 + nt * 16 + l15;
      int slot = chunk ^ (row & 7);
      bp[nt] = *(const short8*)(attL + (row * 16 + slot) * 8);
    }
#pragma unroll
    for (int mt = 0; mt < 4; mt++)
#pragma unroll
      for (int nt = 0; nt < 4; nt++)
        acc[mt * 4 + nt] =
            __builtin_amdgcn_mfma_f32_16x16x32_bf16(aw[mt], bp[nt], acc[mt * 4 + nt], 0, 0, 0);
  }

#pragma unroll
  for (int mt = 0; mt < 4; mt++) {
    int o0 = og * 128 + mh * 64 + mt * 16 + quad * 4;
    float4 bo = *(const float4*)(m1b + o0);
#pragma unroll
    for (int nt = 0; nt < 4; nt++) {
      int px = px0 + nh * 64 + nt * 16 + l15;
      floatx4 v = acc[mt * 4 + nt];
      ushort4 u;
      u.x = f2bf(geluf(v[0] + bo.x));
      u.y = f2bf(geluf(v[1] + bo.y));
      u.z = f2bf(geluf(v[2] + bo.z));
      u.w = f2bf(geluf(v[3] + bo.w));
      *(ushort4*)(mb + ((size_t)b * 65536 + px) * 256 + o0) = u;
    }
  }
}

// K7: m2 = gelu(depthwise 3x3 on 256ch), bf16 -> bf16, channel-innermost [px][c].
// Thread: 4 channels (ushort4) x 1 output row x 64-col sliding window.
// All global loads/stores are 512B-coalesced per wave (lanes cover 256 channels).
__global__ void __launch_bounds__(256) k7_m2(
    const unsigned short* __restrict__ mb, const float* __restrict__ m2w,
    const float* __restrict__ m2b, unsigned short* __restrict__ mb2) {
  int b = blockIdx.y;
  int i0 = (blockIdx.x >> 2) * 4;
  int jq = blockIdx.x & 3;
  int t = threadIdx.x;
  int l = t & 63, ri = t >> 6;
  int co = l * 4;
  int i = i0 + ri;                      // this thread's output row
  int j0 = jq * 64;
  const unsigned short* ibase = mb + ((size_t)b * 65536) * 256 + co;
  unsigned short* obase = mb2 + ((size_t)b * 65536) * 256 + co;

  float w[9][4], bias[4];
#pragma unroll
  for (int cc = 0; cc < 4; cc++) {
    bias[cc] = m2b[co + cc];
#pragma unroll
    for (int tap = 0; tap < 9; tap++) w[tap][cc] = m2w[(co + cc) * 9 + tap];
  }

  // window rows i-1, i, i+1 x cols (j-1, j, j+1) x 4 channels
  float wA[3][4], wB[3][4], wC[3][4];

#define K7_LOAD(dst, ir, jc)                                                        \
  do {                                                                              \
    if ((unsigned)(ir) < 256u && (unsigned)(jc) < 256u) {                           \
      ushort4 u_ = *(const ushort4*)(ibase + ((size_t)((ir) * 256 + (jc))) * 256);  \
      dst[0] = bf2f(u_.x); dst[1] = bf2f(u_.y);                                     \
      dst[2] = bf2f(u_.z); dst[3] = bf2f(u_.w);                                     \
    } else {                                                                        \
      dst[0] = 0.f; dst[1] = 0.f; dst[2] = 0.f; dst[3] = 0.f;                       \
    }                                                                               \
  } while (0)

#pragma unroll
  for (int r = 0; r < 3; r++) {
    K7_LOAD(wA[r], i - 1 + r, j0 - 1);
    K7_LOAD(wB[r], i - 1 + r, j0);
  }

  for (int j = j0; j < j0 + 64; j++) {
#pragma unroll
    for (int r = 0; r < 3; r++) K7_LOAD(wC[r], i - 1 + r, j + 1);
    float acc[4];
#pragma unroll
    for (int cc = 0; cc < 4; cc++) {
      acc[cc] = bias[cc]
        + w[0][cc] * wA[0][cc] + w[1][cc] * wB[0][cc] + w[2][cc] * wC[0][cc]
        + w[3][cc] * wA[1][cc] + w[4][cc] * wB[1][cc] + w[5][cc] * wC[1][cc]
        + w[6][cc] * wA[2][cc] + w[7][cc] * wB[2][cc] + w[8][cc] * wC[2][cc];
    }
    ushort4 u;
    u.x = f2bf(geluf(acc[0]));
    u.y = f2bf(geluf(acc[1]));
    u.z = f2bf(geluf(acc[2]));
    u.w = f2bf(geluf(acc[3]));
    *(ushort4*)(obase + ((size_t)(i * 256 + j)) * 256) = u;
#pragma unroll
    for (int r = 0; r < 3; r++) {
#pragma unroll
      for (int cc = 0; cc < 4; cc++) { wA[r][cc] = wB[r][cc]; wB[r][cc] = wC[r][cc]; }
    }
  }
#undef K7_LOAD
}

// K8: out += conv1x1(m2, 256->128) + m3_b as bf16 MFMA GEMM.
// A = packed weights w8 (m=o), B = m2 pixels from mb2 [px][c(256)] staged to LDS
// in two 128-c halves (slot swizzle). D: row=o, col=px -> fully-coalesced fp32 RMW
// (16 consecutive px per store instruction = 64B lines).
__global__ void __launch_bounds__(256) k8_m3(
    const unsigned short* __restrict__ mb2, const unsigned short* __restrict__ w8,
    const float* __restrict__ m3b, float* __restrict__ out) {
  int px0 = blockIdx.x * 128;
  int b = blockIdx.z;
  int tid = threadIdx.x;
  int wv = tid >> 6, lane = tid & 63;
  int mh = wv & 1, nh = wv >> 1;
  int l15 = lane & 15, quad = lane >> 4;
  __shared__ __align__(16) unsigned short attL[16384];  // 32KB: [n(128)][slot(16)][8]

  floatx4 acc[16];
#pragma unroll
  for (int x = 0; x < 16; x++) acc[x] = floatx4{0.f, 0.f, 0.f, 0.f};

  for (int kk = 0; kk < 2; kk++) {
    if (kk) __syncthreads();
    const unsigned short* src = mb2 + ((size_t)b * 65536 + px0) * 256 + kk * 128;
#pragma unroll
    for (int k = 0; k < 8; k++) {
      int u = k * 256 + tid;
      int n = u >> 4, ch = u & 15;
      short8 v = *(const short8*)(src + (size_t)n * 256 + ch * 8);
      int slot = ch ^ (n & 7);
      *(short8*)(attL + ((size_t)n * 16 + slot) * 8) = v;
    }
    __syncthreads();

#pragma unroll
    for (int step = 0; step < 4; step++) {
      int ch = step * 4 + quad;            // chunk within this 128-c half
      int chg = kk * 16 + ch;              // global chunk (of 32)
      short8 aw[4], bp[4];
#pragma unroll
      for (int mt = 0; mt < 4; mt++) {
        int o = mh * 64 + mt * 16 + l15;
        aw[mt] = *(const short8*)(w8 + ((size_t)chg * 128 + o) * 8);
      }
#pragma unroll
      for (int nt = 0; nt < 4; nt++) {
        int row = nh * 64 + nt * 16 + l15;
        int slot = ch ^ (row & 7);
        bp[nt] = *(const short8*)(attL + (row * 16 + slot) * 8);
      }
#pragma unroll
      for (int mt = 0; mt < 4; mt++)
#pragma unroll
        for (int nt = 0; nt < 4; nt++)
          acc[mt * 4 + nt] =
              __builtin_amdgcn_mfma_f32_16x16x32_bf16(aw[mt], bp[nt], acc[mt * 4 + nt], 0, 0, 0);
    }
  }

#pragma unroll
  for (int mt = 0; mt < 4; mt++) {
    int o0 = mh * 64 + mt * 16 + quad * 4;
    float4 bo = *(const float4*)(m3b + o0);
#pragma unroll
    for (int nt = 0; nt < 4; nt++) {
      int px = px0 + nh * 64 + nt * 16 + l15;
      floatx4 v = acc[mt * 4 + nt];
      size_t a0 = ((size_t)(b * 128 + o0 + 0)) * NHW + px;
      size_t a1 = ((size_t)(b * 128 + o0 + 1)) * NHW + px;
      size_t a2 = ((size_t)(b * 128 + o0 + 2)) * NHW + px;
      size_t a3 = ((size_t)(b * 128 + o0 + 3)) * NHW + px;
      out[a0] += v[0] + bo.x;
      out[a1] += v[1] + bo.y;
      out[a2] += v[2] + bo.z;
      out[a3] += v[3] + bo.w;
    }
  }
}

extern "C" void kernel_launch(void* const* d_in, const int* in_sizes, int n_in,
                              void* d_out, int out_size, void* d_ws, size_t ws_size,
                              hipStream_t stream) {
  const float* x1  = (const float*)d_in[0];
  const float* x2  = (const float*)d_in[1];
  const float* q1w = (const float*)d_in[2];  const float* q1b = (const float*)d_in[3];
  const float* q2w = (const float*)d_in[4];  const float* q2b = (const float*)d_in[5];
  const float* k1w = (const float*)d_in[6];  const float* k1b = (const float*)d_in[7];
  const float* k2w = (const float*)d_in[8];  const float* k2b = (const float*)d_in[9];
  const float* v1w = (const float*)d_in[10]; const float* v1b = (const float*)d_in[11];
  const float* v2w = (const float*)d_in[12]; const float* v2b = (const float*)d_in[13];
  const float* rw  = (const float*)d_in[14]; const float* rb  = (const float*)d_in[15];
  const float* m1w = (const float*)d_in[16]; const float* m1b = (const float*)d_in[17];
  const float* m2w = (const float*)d_in[18]; const float* m2b = (const float*)d_in[19];
  const float* m3w = (const float*)d_in[20]; const float* m3b = (const float*)d_in[21];
  float* ws = (float*)d_ws;
  float* out = (float*)d_out;
  unsigned short* mb  = (unsigned short*)d_ws;            // [px][o(256)] after k6
  unsigned short* mb2 = (unsigned short*)d_ws + MB2_US;   // [px][c(256)] after k7
  unsigned short* a16 = (unsigned short*)d_ws + A16_US;
  unsigned short* w6  = (unsigned short*)d_ws + W6_US;
  unsigned short* w8  = (unsigned short*)d_ws + W8_US;    // written after k7 (dead mb region)
  unsigned short* attB = (unsigned short*)(ws + OFF_ATT);
  unsigned short* wAu  = (unsigned short*)(ws + OFF_RWT);

  (void)hipMemsetAsync((char*)d_ws + OFF_CTX * sizeof(float), 0, (4096 + 256) * sizeof(float), stream);
  k0_wprep<<<800, 256, 0, stream>>>(rw, wAu);
  k0b_w6<<<128, 256, 0, stream>>>(m1w, w6);
  k1_qkv<<<1024, 256, 0, stream>>>(x1, x2, q1w, q1b, k1w, k1b, v1w, v1b, ws);
  k2_dw<<<dim3(16, 64, 4), 256, 0, stream>>>(ws, k2w, k2b, k1b, v2w, v2b);
  k3_ctx<<<128, 256, 0, stream>>>(ws);
  k4_att<<<512, 256, 0, stream>>>(ws, q2w, q2b, q1b);
  k5_mfma<<<dim3(256, 2, 4), 256, 0, stream>>>(attB, wAu, rb, out, a16);
  k6_m1<<<dim3(512, 2, 4), 256, 0, stream>>>(a16, w6, m1b, mb);
  k7_m2<<<dim3(256, 4), 256, 0, stream>>>(mb, m2w, m2b, mb2);
  k0c_w8<<<128, 256, 0, stream>>>(m3w, w8);
  k8_m3<<<dim3(512, 1, 4), 256, 0, stream>>>(mb2, w8, m3b, out);
}

// Round 5
// 931.330 us; speedup vs baseline: 1.7521x; 1.0784x over previous
//
#include <hip/hip_runtime.h>
#include <hip/hip_bf16.h>
#include <cstdint>

#define NHW 65536
#define NSQ 32768

// workspace layout (float slots)
static constexpr size_t OFF_AQ  = 0;          // (4,64,256,128) conv1x1_q at nonanchor (squeezed)
static constexpr size_t OFF_AK  = 8388608;    // (4,64,256,128) conv1x1_k at anchor (squeezed)
static constexpr size_t OFF_AV  = 16777216;   // (4,64,256,256) conv1x1_v full res
static constexpr size_t OFF_EK  = 33554432;   // (4,64,256,128) exp(k_dw) squeezed
static constexpr size_t OFF_VD  = 41943040;   // (4,64,256,128) v_dw squeezed
static constexpr size_t OFF_ATT = 50331648;   // bf16 (4,256,128,64) att squeezed, channel-innermost
static constexpr size_t OFF_CTX = 58720256;   // 4*4*16*16
static constexpr size_t OFF_Z   = 58724352;   // 4*64
static constexpr size_t OFF_RWT = 58724608;   // bf16 wA[tap(25)][c/8(8)][o(128)][c%8(8)] = 204800 ushorts
static constexpr size_t MB2_US  = 67108864;   // ushort offset of mb2 [px][c] (mb at 0) - phases don't overlap
// bf16 attention [b][pixel][o(128)] - lives only between k5 and k6 (region later clobbered by mb2)
static constexpr size_t A16_US  = 67108864;   // 33.55M ushorts
// bf16 packed m1 weights [chunk(16)][o(256)][8] - after wAu's ushort extent
static constexpr size_t W6_US   = 117654016;  // 32768 ushorts
// bf16 packed qkv 1x1 weights [mat(3)][chunk(8)][o(64)][cj(8)] - after w6
static constexpr size_t WQKV_US = 117686784;  // 12288 ushorts
// bf16 packed m3 weights [chunk(32)][o(128)][8] - at ushort 0 (dead mb region),
// written by k0c AFTER k7 (k7's mb2 write clobbers the W6 tail region).
static constexpr size_t W8_US   = 0;          // 32768 ushorts

typedef __attribute__((ext_vector_type(8))) short short8;
typedef __attribute__((ext_vector_type(4))) float floatx4;

// tap tables: first 13 = even parity (kh+kw even), last 12 = odd parity
__device__ __constant__ int TKH[25] = {0,0,0,1,1,2,2,2,3,3,4,4,4,  0,0,1,1,1,2,2,3,3,3,4,4};
__device__ __constant__ int TKW[25] = {0,2,4,1,3,0,2,4,1,3,0,2,4,  1,3,0,2,4,1,3,0,2,4,1,3};

__device__ __forceinline__ float geluf(float x) {
  return 0.5f * x * (1.0f + erff(x * 0.70710678118654752440f));
}
__device__ __forceinline__ unsigned short f2bf(float f) {
  union { float f; uint32_t u; } v; v.f = f;
  uint32_t x = v.u;
  uint32_t r = x + 0x7fffu + ((x >> 16) & 1u);
  return (unsigned short)(r >> 16);
}
__device__ __forceinline__ float bf2f(unsigned short u) {
  union { uint32_t i; float f; } v; v.i = ((uint32_t)u) << 16; return v.f;
}

// K0: prep conv5 weights into A-fragment order: wA[tap][c/8][o][c%8] bf16
__global__ void __launch_bounds__(256) k0_wprep(const float* __restrict__ rw,
                                                unsigned short* __restrict__ wAu) {
  int idx = blockIdx.x * 256 + threadIdx.x;   // 204800 total
  int cj = idx & 7, o = (idx >> 3) & 127, chunk = (idx >> 10) & 7, tap = idx >> 13;
  int c = chunk * 8 + cj;
  int t = TKH[tap] * 5 + TKW[tap];
  wAu[idx] = f2bf(rw[(o * 64 + c) * 25 + t]);
}

// K0b: pack m1 weights to bf16 fragment order: w6[chunk(16)][o(256)][cj(8)]
__global__ void __launch_bounds__(256) k0b_w6(const float* __restrict__ m1w,
                                              unsigned short* __restrict__ w6) {
  int idx = blockIdx.x * 256 + threadIdx.x;   // 32768 total
  int cj = idx & 7, o = (idx >> 3) & 255, chunk = idx >> 11;
  w6[idx] = f2bf(m1w[o * 128 + chunk * 8 + cj]);
}

// K0c: pack m3 weights to bf16 fragment order: w8[chunk(32)][o(128)][cj(8)]
__global__ void __launch_bounds__(256) k0c_w8(const float* __restrict__ m3w,
                                              unsigned short* __restrict__ w8) {
  int idx = blockIdx.x * 256 + threadIdx.x;   // 32768 total
  int cj = idx & 7, o = (idx >> 3) & 127, chunk = idx >> 10;
  w8[idx] = f2bf(m3w[o * 256 + chunk * 8 + cj]);
}

// K0d: pack q1/k1/v1 1x1 weights: wqkv[mat(3)][chunk(8)][o(64)][cj(8)] bf16
__global__ void __launch_bounds__(256) k0d_wqkv(
    const float* __restrict__ q1w, const float* __restrict__ k1w,
    const float* __restrict__ v1w, unsigned short* __restrict__ wqkv) {
  int idx = blockIdx.x * 256 + threadIdx.x;   // 12288 total
  int cj = idx & 7, o = (idx >> 3) & 63, chunk = (idx >> 9) & 7, mat = idx >> 12;
  const float* src = mat == 0 ? q1w : (mat == 1 ? k1w : v1w);
  wqkv[idx] = f2bf(src[o * 64 + chunk * 8 + cj]);
}

// K1: 1x1 convs as bf16 MFMA GEMMs. Per (b, row i) block:
// stage x1 row bf16 [j(256)][slot(8)][8ch] (slot = chunk^((j>>1)&7), <=2-way banks),
// GEMM q (nonanchor cols) + k (anchor cols); restage x2, GEMM v (all cols).
// Weights read direct from global wqkv (L1-resident). Outputs same layout as before.
__global__ void __launch_bounds__(256) k1_qkv(
    const float* __restrict__ x1, const float* __restrict__ x2,
    const unsigned short* __restrict__ wqkv,
    const float* __restrict__ q1b, const float* __restrict__ k1b,
    const float* __restrict__ v1b, float* ws) {
  int b = blockIdx.x >> 8, i = blockIdx.x & 255;
  int tid = threadIdx.x;
  int wv = tid >> 6, lane = tid & 63;
  int mh = wv & 1, nh = wv >> 1;
  int l15 = lane & 15, quad = lane >> 4;
  __shared__ __align__(16) unsigned short xL[16384];  // 32KB [j(256)][slot(8)][8]

  // ---- stage x1 row as bf16 ----
  {
    const float* xr = x1 + ((size_t)b * 64) * NHW + i * 256;
#pragma unroll
    for (int u = 0; u < 8; u++) {
      int idx = u * 256 + tid;
      int j = idx & 255, chunk = idx >> 8;
      short8 v;
#pragma unroll
      for (int cj = 0; cj < 8; cj++)
        v[cj] = (short)f2bf(xr[(size_t)(chunk * 8 + cj) * NHW + j]);
      int slot = chunk ^ ((j >> 1) & 7);
      *(short8*)(xL + (size_t)(j * 8 + slot) * 8) = v;
    }
  }
  __syncthreads();

  int s_na = i & 1, s_a = 1 - s_na;

  floatx4 accq[8], acck[8];
#pragma unroll
  for (int x = 0; x < 8; x++) {
    accq[x] = floatx4{0.f, 0.f, 0.f, 0.f};
    acck[x] = floatx4{0.f, 0.f, 0.f, 0.f};
  }

#pragma unroll
  for (int chalf = 0; chalf < 2; chalf++) {
    int chunk = chalf * 4 + quad;
    short8 awq[2], awk[2], bq[4], bk[4];
#pragma unroll
    for (int mt = 0; mt < 2; mt++) {
      int o = mh * 32 + mt * 16 + l15;
      awq[mt] = *(const short8*)(wqkv + ((size_t)(0 * 8 + chunk) * 64 + o) * 8);
      awk[mt] = *(const short8*)(wqkv + ((size_t)(1 * 8 + chunk) * 64 + o) * 8);
    }
#pragma unroll
    for (int nt = 0; nt < 4; nt++) {
      int jp = nh * 64 + nt * 16 + l15;
      int slot = chunk ^ (jp & 7);
      int jq = 2 * jp + s_na, jk = 2 * jp + s_a;
      bq[nt] = *(const short8*)(xL + (size_t)(jq * 8 + slot) * 8);
      bk[nt] = *(const short8*)(xL + (size_t)(jk * 8 + slot) * 8);
    }
#pragma unroll
    for (int mt = 0; mt < 2; mt++)
#pragma unroll
      for (int nt = 0; nt < 4; nt++) {
        accq[mt * 4 + nt] =
            __builtin_amdgcn_mfma_f32_16x16x32_bf16(awq[mt], bq[nt], accq[mt * 4 + nt], 0, 0, 0);
        acck[mt * 4 + nt] =
            __builtin_amdgcn_mfma_f32_16x16x32_bf16(awk[mt], bk[nt], acck[mt * 4 + nt], 0, 0, 0);
      }
  }

  // store q -> AQ (nonanchor squeezed), k -> AK (anchor squeezed)
#pragma unroll
  for (int mt = 0; mt < 2; mt++) {
    int o0 = mh * 32 + mt * 16 + quad * 4;
    float4 bq4 = *(const float4*)(q1b + o0);
    float4 bk4 = *(const float4*)(k1b + o0);
#pragma unroll
    for (int nt = 0; nt < 4; nt++) {
      int jp = nh * 64 + nt * 16 + l15;
      floatx4 vq = accq[mt * 4 + nt];
      floatx4 vk = acck[mt * 4 + nt];
      float* dq = ws + OFF_AQ + ((size_t)(b * 64 + o0)) * NSQ + i * 128 + jp;
      float* dk = ws + OFF_AK + ((size_t)(b * 64 + o0)) * NSQ + i * 128 + jp;
      dq[0 * NSQ] = vq[0] + bq4.x; dq[1 * NSQ] = vq[1] + bq4.y;
      dq[2 * NSQ] = vq[2] + bq4.z; dq[3 * NSQ] = vq[3] + bq4.w;
      dk[0 * NSQ] = vk[0] + bk4.x; dk[1 * NSQ] = vk[1] + bk4.y;
      dk[2 * NSQ] = vk[2] + bk4.z; dk[3 * NSQ] = vk[3] + bk4.w;
    }
  }

  __syncthreads();
  // ---- stage x2 row ----
  {
    const float* xr = x2 + ((size_t)b * 64) * NHW + i * 256;
#pragma unroll
    for (int u = 0; u < 8; u++) {
      int idx = u * 256 + tid;
      int j = idx & 255, chunk = idx >> 8;
      short8 v;
#pragma unroll
      for (int cj = 0; cj < 8; cj++)
        v[cj] = (short)f2bf(xr[(size_t)(chunk * 8 + cj) * NHW + j]);
      int slot = chunk ^ ((j >> 1) & 7);
      *(short8*)(xL + (size_t)(j * 8 + slot) * 8) = v;
    }
  }
  __syncthreads();

  floatx4 accv[16];
#pragma unroll
  for (int x = 0; x < 16; x++) accv[x] = floatx4{0.f, 0.f, 0.f, 0.f};

#pragma unroll
  for (int chalf = 0; chalf < 2; chalf++) {
    int chunk = chalf * 4 + quad;
    short8 awv[2], bv[8];
#pragma unroll
    for (int mt = 0; mt < 2; mt++) {
      int o = mh * 32 + mt * 16 + l15;
      awv[mt] = *(const short8*)(wqkv + ((size_t)(2 * 8 + chunk) * 64 + o) * 8);
    }
#pragma unroll
    for (int nt = 0; nt < 8; nt++) {
      int j = nh * 128 + nt * 16 + l15;
      int slot = chunk ^ ((j >> 1) & 7);
      bv[nt] = *(const short8*)(xL + (size_t)(j * 8 + slot) * 8);
    }
#pragma unroll
    for (int mt = 0; mt < 2; mt++)
#pragma unroll
      for (int nt = 0; nt < 8; nt++)
        accv[mt * 8 + nt] =
            __builtin_amdgcn_mfma_f32_16x16x32_bf16(awv[mt], bv[nt], accv[mt * 8 + nt], 0, 0, 0);
  }

  // store v -> AV full res
#pragma unroll
  for (int mt = 0; mt < 2; mt++) {
    int o0 = mh * 32 + mt * 16 + quad * 4;
    float4 bv4 = *(const float4*)(v1b + o0);
#pragma unroll
    for (int nt = 0; nt < 8; nt++) {
      int j = nh * 128 + nt * 16 + l15;
      floatx4 vv = accv[mt * 8 + nt];
      float* dv = ws + OFF_AV + ((size_t)(b * 64 + o0)) * NHW + i * 256 + j;
      dv[0 * NHW] = vv[0] + bv4.x; dv[1 * NHW] = vv[1] + bv4.y;
      dv[2 * NHW] = vv[2] + bv4.z; dv[3 * NHW] = vv[3] + bv4.w;
    }
  }
}

// K2: k depthwise (5 real taps + bias correction) -> exp; v depthwise (9 taps, full res);
// accumulate Z[b,c] = sum exp(kdw).
// Band-tiled: block stages 18 rows of AK (squeezed, 128 cols) and AV (full, 256 cols)
// into LDS with zero-padded halo cols/rows (branchless taps). Thread computes 8
// consecutive jp outputs; float4 stores; one atomicAdd per block.
__global__ void __launch_bounds__(256) k2_dw(
    float* ws,
    const float* __restrict__ kw2, const float* __restrict__ kb2, const float* __restrict__ kb1,
    const float* __restrict__ vw2, const float* __restrict__ vb2) {
  int ig = blockIdx.x, c = blockIdx.y, b = blockIdx.z;
  int i0 = ig * 16;
  int tid = threadIdx.x;

  __shared__ float akL[18][130];   // col k at index k+1; pads at 0 and 129
  __shared__ float avL[18][260];   // col j at index j+1; pads at 0 and 257
  __shared__ float red[256];

  const float* AKg = ws + OFF_AK + ((size_t)(b * 64 + c)) * NSQ;
  const float* AVg = ws + OFF_AV + ((size_t)(b * 64 + c)) * NHW;

  for (int idx = tid; idx < 18 * 128; idx += 256) {
    int r = idx >> 7, col = idx & 127;
    int gi = i0 - 1 + r;
    akL[r][1 + col] = (gi >= 0 && gi < 256) ? AKg[gi * 128 + col] : 0.f;
  }
  for (int idx = tid; idx < 18 * 256; idx += 256) {
    int r = idx >> 8, col = idx & 255;
    int gi = i0 - 1 + r;
    avL[r][1 + col] = (gi >= 0 && gi < 256) ? AVg[gi * 256 + col] : 0.f;
  }
  if (tid < 18) {
    akL[tid][0] = 0.f; akL[tid][129] = 0.f;
    avL[tid][0] = 0.f; avL[tid][257] = 0.f;
  }
  __syncthreads();

  int tr = tid >> 4, tj = tid & 15;
  int i = i0 + tr;
  int jp0 = tj * 8;
  int li = tr + 1;
  int s = 1 - (i & 1);                  // anchor: col = 2*jp + s

  const float* w9 = kw2 + c * 9;
  float kw0 = w9[0], kw1 = w9[1], kw2c = w9[2], kw3 = w9[3], kw4 = w9[4],
        kw5 = w9[5], kw6 = w9[6], kw7 = w9[7], kw8 = w9[8];
  float kb2c = kb2[c], kb1c = kb1[c];
  const float* vwp = vw2 + c * 9;
  float vw0 = vwp[0], vw1 = vwp[1], vw2v = vwp[2], vw3 = vwp[3], vw4 = vwp[4],
        vw5 = vwp[5], vw6 = vwp[6], vw7 = vwp[7], vw8 = vwp[8];
  float vbc = vb2[c];

  float ek[8], vd[8];
  float zsum = 0.f;
#pragma unroll
  for (int u = 0; u < 8; u++) {
    int jp = jp0 + u;
    int j = 2 * jp + s;
    float bs = 0.f;
    if (i > 0)   bs += kw1;
    if (i < 255) bs += kw7;
    if (j > 0)   bs += kw3;
    if (j < 255) bs += kw5;
    // K-path: masked taps read zero-pads -> identical to original skip semantics
    float acc = kb2c + kb1c * bs
      + kw4 * akL[li][1 + jp]
      + kw0 * akL[li - 1][jp + s] + kw2c * akL[li - 1][1 + jp + s]
      + kw6 * akL[li + 1][jp + s] + kw8 * akL[li + 1][1 + jp + s];
    float e = expf(acc);
    ek[u] = e; zsum += e;
    // V-path: 9 taps, full-res cols j-1..j+1 at LDS index j..j+2
    vd[u] = vbc
      + vw0 * avL[li - 1][j] + vw1 * avL[li - 1][1 + j] + vw2v * avL[li - 1][2 + j]
      + vw3 * avL[li    ][j] + vw4 * avL[li    ][1 + j] + vw5  * avL[li    ][2 + j]
      + vw6 * avL[li + 1][j] + vw7 * avL[li + 1][1 + j] + vw8  * avL[li + 1][2 + j];
  }

  float* ekp = ws + OFF_EK + ((size_t)(b * 64 + c)) * NSQ + i * 128 + jp0;
  float* vdp = ws + OFF_VD + ((size_t)(b * 64 + c)) * NSQ + i * 128 + jp0;
  float4 e0 = {ek[0], ek[1], ek[2], ek[3]}, e1 = {ek[4], ek[5], ek[6], ek[7]};
  float4 v0 = {vd[0], vd[1], vd[2], vd[3]}, v1 = {vd[4], vd[5], vd[6], vd[7]};
  *(float4*)(ekp) = e0; *(float4*)(ekp + 4) = e1;
  *(float4*)(vdp) = v0; *(float4*)(vdp + 4) = v1;

  red[tid] = zsum;
  __syncthreads();
#pragma unroll
  for (int off = 128; off > 0; off >>= 1) {
    if (tid < off) red[tid] += red[tid + off];
    __syncthreads();
  }
  if (tid == 0) atomicAdd(ws + OFF_Z + (b * 64 + c), red[0]);
}

// K3: ctx_raw[b,h,d,e] = sum_n ek[b,h*16+d,n] * vdw[b,h*16+e,n]
__global__ void __launch_bounds__(256) k3_ctx(float* ws) {
  int bid = blockIdx.x;                 // 4*4*8
  int b = bid >> 5, h = (bid >> 3) & 3, ch = bid & 7;
  int n0 = ch * 4096;
  int tid = threadIdx.x;
  int d = tid >> 4, e = tid & 15;
  __shared__ float ekt[16][260];
  __shared__ float vdt[16][260];
  const float* ekb = ws + OFF_EK + ((size_t)(b * 64 + h * 16)) * NSQ + n0;
  const float* vdb = ws + OFF_VD + ((size_t)(b * 64 + h * 16)) * NSQ + n0;
  float acc = 0.f;
  for (int sub = 0; sub < 16; sub++) {
    __syncthreads();
#pragma unroll
    for (int r = 0; r < 16; r++) {
      ekt[r][tid] = ekb[(size_t)r * NSQ + sub * 256 + tid];
      vdt[r][tid] = vdb[(size_t)r * NSQ + sub * 256 + tid];
    }
    __syncthreads();
#pragma unroll 8
    for (int x = 0; x < 256; x++) acc += ekt[d][x] * vdt[e][x];
  }
  atomicAdd(ws + OFF_CTX + ((b * 4 + h) * 16 + d) * 16 + e, acc);
}

// K4: q depthwise + softmax over d, att[e] = sum_d (ctx_raw/Z)[d,e]*qsoft[d];
// store bf16, channel-innermost [b][i][jp][c]
__global__ void __launch_bounds__(256) k4_att(
    float* ws,
    const float* __restrict__ qw2, const float* __restrict__ qb2, const float* __restrict__ qb1) {
  int b = blockIdx.x >> 7, ip = blockIdx.x & 127;
  int tid = threadIdx.x;
  int i = ip * 2 + (tid >> 7);
  int jp = tid & 127;
  __shared__ float ctxn[1024];
  for (int idx = tid; idx < 1024; idx += 256)
    ctxn[idx] = ws[OFF_CTX + b * 1024 + idx] / ws[OFF_Z + b * 64 + (idx >> 4)];
  __syncthreads();
  int s = i & 1;                        // nonanchor: col = 2*jp + s
  int j = 2 * jp + s;
  int cl = jp - 1 + s, cr = jp + s;
  unsigned short* attB = (unsigned short*)(ws + OFF_ATT);
  unsigned short* dstp = attB + (((size_t)(b * 256 + i)) * 128 + jp) * 64;
  for (int h = 0; h < 4; h++) {
    float qv[16];
#pragma unroll
    for (int dc = 0; dc < 16; dc++) {
      int c = h * 16 + dc;
      const float* AQ = ws + OFF_AQ + ((size_t)(b * 64 + c)) * NSQ;
      const float* w9 = qw2 + c * 9;
      float acc = qb2[c] + w9[4] * AQ[i * 128 + jp];
      if (i > 0) {
        const float* r = AQ + (i - 1) * 128;
        if (cl >= 0)   acc += w9[0] * r[cl];
        if (cr <= 127) acc += w9[2] * r[cr];
      }
      if (i < 255) {
        const float* r = AQ + (i + 1) * 128;
        if (cl >= 0)   acc += w9[6] * r[cl];
        if (cr <= 127) acc += w9[8] * r[cr];
      }
      float bs = 0.f;
      if (i > 0)   bs += w9[1];
      if (i < 255) bs += w9[7];
      if (j > 0)   bs += w9[3];
      if (j < 255) bs += w9[5];
      qv[dc] = acc + qb1[c] * bs;
    }
    float mx = qv[0];
#pragma unroll
    for (int dc = 1; dc < 16; dc++) mx = fmaxf(mx, qv[dc]);
    float sum = 0.f;
#pragma unroll
    for (int dc = 0; dc < 16; dc++) { qv[dc] = expf(qv[dc] - mx); sum += qv[dc]; }
    float inv = 1.0f / sum;
#pragma unroll
    for (int e = 0; e < 16; e++) {
      float a = 0.f;
#pragma unroll
      for (int dc = 0; dc < 16; dc++) a += ctxn[h * 256 + dc * 16 + e] * qv[dc];
      dstp[h * 16 + e] = f2bf(a * inv);
    }
  }
}

// K5: 5x5 conv 64->128ch over checkerboard-sparse att, as bf16 MFMA implicit GEMM.
// Per (b, parity): C[o=128][n=128 px (4 rows x 32 jp)] = sum_{tap,c} W[o][tap,c]*Att[tap,c][n].
// attL layout [lr(8)][cb(3)][pos(16)][slot=chunk^(pos&7)][8ch] -> conflict-free b128 r/w.
// Epilogue also emits bf16 attention in [b][pixel][o(128)] layout for k6's MFMA.
__global__ void __launch_bounds__(256) k5_mfma(
    const unsigned short* __restrict__ attB, const unsigned short* __restrict__ wAu,
    const float* __restrict__ rb, float* __restrict__ out,
    unsigned short* __restrict__ a16) {
  int p = blockIdx.y, b = blockIdx.z;
  int i0 = (blockIdx.x >> 2) * 4;
  int jp0 = (blockIdx.x & 3) * 32;
  int tid = threadIdx.x;
  int wv = tid >> 6, lane = tid & 63;
  int mh = wv & 1, nh = wv >> 1;
  int l15 = lane & 15, quad = lane >> 4;

  __shared__ __align__(16) unsigned short attL[24576];  // 48KB: X16=((lr*3+cb)*16+pos)*8+slot
  __shared__ __align__(16) unsigned short wL[8192];     // 16KB: X16=(chalf*4+quad)*128+o

  // stage att tile (8 rows x 48 cols x 64 ch): 3072 16B units
  const unsigned short* attBase = attB + ((size_t)b * 256) * 128 * 64;
  for (int k = 0; k < 12; k++) {
    int u = k * 256 + tid;
    int chunk = u & 7;
    int pos = (u >> 3) & 15;
    int cbr = u >> 7;                  // lr*3+cb, 0..23
    int cb = cbr % 3, lr = cbr / 3;
    int r = i0 - 2 + lr;
    int jp = jp0 - 2 + cb * 16 + pos;
    short8 v = {0, 0, 0, 0, 0, 0, 0, 0};
    if (r >= 0 && r < 256 && jp >= 0 && jp < 128)
      v = *(const short8*)(attBase + (((size_t)r * 128) + jp) * 64 + chunk * 8);
    int slot = chunk ^ (pos & 7);
    *(short8*)(attL + (((size_t)cbr * 16 + pos) * 8 + slot) * 8) = v;
  }

  floatx4 acc[16];
#pragma unroll
  for (int x = 0; x < 16; x++) acc[x] = floatx4{0.f, 0.f, 0.f, 0.f};

  int riv[4], ci2[4];
#pragma unroll
  for (int nt = 0; nt < 4; nt++) {
    int ntg = nh * 4 + nt;
    riv[nt] = ntg >> 1;
    ci2[nt] = (ntg & 1) * 16 + l15 + 2;
  }

  int t0 = p ? 13 : 0;
  int ntaps = p ? 12 : 13;
  for (int tt = 0; tt < ntaps; tt++) {
    int tap = t0 + tt;
    int kh = TKH[tap], kw = TKW[tap];
    __syncthreads();
    {
      const short8* src = (const short8*)(wAu + (size_t)tap * 8192);
      short8* dst = (short8*)wL;
#pragma unroll
      for (int k = 0; k < 4; k++) dst[k * 256 + tid] = src[k * 256 + tid];
    }
    __syncthreads();
#pragma unroll
    for (int chalf = 0; chalf < 2; chalf++) {
      short8 a[4], bf[4];
#pragma unroll
      for (int mt = 0; mt < 4; mt++)
        a[mt] = *(const short8*)(wL + (((chalf * 4 + quad) * 128) + mh * 64 + mt * 16 + l15) * 8);
#pragma unroll
      for (int nt = 0; nt < 4; nt++) {
        int lr = riv[nt] + kh;
        int off = ((kw - 2) + ((p + riv[nt]) & 1) - ((riv[nt] + kh) & 1)) >> 1;
        int lc = ci2[nt] + off;
        int cb = lc >> 4, pos = lc & 15;
        int slot = (chalf * 4 + quad) ^ (pos & 7);
        bf[nt] = *(const short8*)(attL + ((((lr * 3 + cb) * 16 + pos) * 8) + slot) * 8);
      }
#pragma unroll
      for (int mt = 0; mt < 4; mt++)
#pragma unroll
        for (int nt = 0; nt < 4; nt++)
          acc[mt * 4 + nt] =
              __builtin_amdgcn_mfma_f32_16x16x32_bf16(a[mt], bf[nt], acc[mt * 4 + nt], 0, 0, 0);
    }
  }

  // epilogue: D row = o = mh*64+mt*16+quad*4+reg, col = n = lane&15 within n-tile
#pragma unroll
  for (int mt = 0; mt < 4; mt++) {
#pragma unroll
    for (int nt = 0; nt < 4; nt++) {
      int ntg = nh * 4 + nt;
      int i = i0 + (ntg >> 1);
      int jp = jp0 + (ntg & 1) * 16 + l15;
      int j = 2 * jp + ((p + i) & 1);
      floatx4 v = acc[mt * 4 + nt];
      int o0 = mh * 64 + mt * 16 + quad * 4;
      ushort4 u4;
      float r0 = v[0] + rb[o0 + 0];
      float r1 = v[1] + rb[o0 + 1];
      float r2 = v[2] + rb[o0 + 2];
      float r3 = v[3] + rb[o0 + 3];
      out[(((size_t)(b * 128 + o0 + 0)) * 256 + i) * 256 + j] = r0;
      out[(((size_t)(b * 128 + o0 + 1)) * 256 + i) * 256 + j] = r1;
      out[(((size_t)(b * 128 + o0 + 2)) * 256 + i) * 256 + j] = r2;
      out[(((size_t)(b * 128 + o0 + 3)) * 256 + i) * 256 + j] = r3;
      u4.x = f2bf(r0); u4.y = f2bf(r1); u4.z = f2bf(r2); u4.w = f2bf(r3);
      *(ushort4*)(a16 + ((size_t)b * 65536 + (size_t)i * 256 + j) * 128 + o0) = u4;
    }
  }
}

// K6: m1 = gelu(conv1x1 128->256) as bf16 MFMA GEMM.
// A = packed weights w6 (m=o), B = attention pixels from a16 [px][c] staged in LDS
// (slot swizzle). D: row=o (4 consecutive per lane via regs), col=px ->
// ushort4-along-o stores into mb [px][o(256)] channel-innermost layout.
__global__ void __launch_bounds__(256) k6_m1(
    const unsigned short* __restrict__ a16, const unsigned short* __restrict__ w6,
    const float* __restrict__ m1b, unsigned short* __restrict__ mb) {
  int px0 = blockIdx.x * 128;
  int og = blockIdx.y, b = blockIdx.z;
  int tid = threadIdx.x;
  int wv = tid >> 6, lane = tid & 63;
  int mh = wv & 1, nh = wv >> 1;
  int l15 = lane & 15, quad = lane >> 4;
  __shared__ __align__(16) unsigned short attL[16384];  // 32KB: [n(128)][slot(16)][8]

  const unsigned short* src = a16 + ((size_t)b * 65536 + px0) * 128;
#pragma unroll
  for (int k = 0; k < 8; k++) {
    int u = k * 256 + tid;
    int n = u >> 4, chunk = u & 15;
    short8 v = *(const short8*)(src + (size_t)n * 128 + chunk * 8);
    int slot = chunk ^ (n & 7);
    *(short8*)(attL + ((size_t)n * 16 + slot) * 8) = v;
  }
  __syncthreads();

  floatx4 acc[16];
#pragma unroll
  for (int x = 0; x < 16; x++) acc[x] = floatx4{0.f, 0.f, 0.f, 0.f};

#pragma unroll
  for (int step = 0; step < 4; step++) {
    int chunk = step * 4 + quad;
    short8 aw[4], bp[4];
#pragma unroll
    for (int mt = 0; mt < 4; mt++) {
      int o = og * 128 + mh * 64 + mt * 16 + l15;
      aw[mt] = *(const short8*)(w6 + ((size_t)chunk * 256 + o) * 8);
    }
#pragma unroll
    for (int nt = 0; nt < 4; nt++) {
      int row = nh * 64 + nt * 16 + l15;
      int slot = chunk ^ (row & 7);
      bp[nt] = *(const short8*)(attL + (row * 16 + slot) * 8);
    }
#pragma unroll
    for (int mt = 0; mt < 4; mt++)
#pragma unroll
      for (int nt = 0; nt < 4; nt++)
        acc[mt * 4 + nt] =
            __builtin_amdgcn_mfma_f32_16x16x32_bf16(aw[mt], bp[nt], acc[mt * 4 + nt], 0, 0, 0);
  }

#pragma unroll
  for (int mt = 0; mt < 4; mt++) {
    int o0 = og * 128 + mh * 64 + mt * 16 + quad * 4;
    float4 bo = *(const float4*)(m1b + o0);
#pragma unroll
    for (int nt = 0; nt < 4; nt++) {
      int px = px0 + nh * 64 + nt * 16 + l15;
      floatx4 v = acc[mt * 4 + nt];
      ushort4 u;
      u.x = f2bf(geluf(v[0] + bo.x));
      u.y = f2bf(geluf(v[1] + bo.y));
      u.z = f2bf(geluf(v[2] + bo.z));
      u.w = f2bf(geluf(v[3] + bo.w));
      *(ushort4*)(mb + ((size_t)b * 65536 + px) * 256 + o0) = u;
    }
  }
}

// K7: m2 = gelu(depthwise 3x3 on 256ch), bf16 -> bf16, channel-innermost [px][c].
// Thread: 4 channels (ushort4) x 1 output row x 64-col sliding window.
// All global loads/stores are 512B-coalesced per wave (lanes cover 256 channels).
__global__ void __launch_bounds__(256) k7_m2(
    const unsigned short* __restrict__ mb, const float* __restrict__ m2w,
    const float* __restrict__ m2b, unsigned short* __restrict__ mb2) {
  int b = blockIdx.y;
  int i0 = (blockIdx.x >> 2) * 4;
  int jq = blockIdx.x & 3;
  int t = threadIdx.x;
  int l = t & 63, ri = t >> 6;
  int co = l * 4;
  int i = i0 + ri;                      // this thread's output row
  int j0 = jq * 64;
  const unsigned short* ibase = mb + ((size_t)b * 65536) * 256 + co;
  unsigned short* obase = mb2 + ((size_t)b * 65536) * 256 + co;

  float w[9][4], bias[4];
#pragma unroll
  for (int cc = 0; cc < 4; cc++) {
    bias[cc] = m2b[co + cc];
#pragma unroll
    for (int tap = 0; tap < 9; tap++) w[tap][cc] = m2w[(co + cc) * 9 + tap];
  }

  // window rows i-1, i, i+1 x cols (j-1, j, j+1) x 4 channels
  float wA[3][4], wB[3][4], wC[3][4];

#define K7_LOAD(dst, ir, jc)                                                        \
  do {                                                                              \
    if ((unsigned)(ir) < 256u && (unsigned)(jc) < 256u) {                           \
      ushort4 u_ = *(const ushort4*)(ibase + ((size_t)((ir) * 256 + (jc))) * 256);  \
      dst[0] = bf2f(u_.x); dst[1] = bf2f(u_.y);                                     \
      dst[2] = bf2f(u_.z); dst[3] = bf2f(u_.w);                                     \
    } else {                                                                        \
      dst[0] = 0.f; dst[1] = 0.f; dst[2] = 0.f; dst[3] = 0.f;                       \
    }                                                                               \
  } while (0)

#pragma unroll
  for (int r = 0; r < 3; r++) {
    K7_LOAD(wA[r], i - 1 + r, j0 - 1);
    K7_LOAD(wB[r], i - 1 + r, j0);
  }

  for (int j = j0; j < j0 + 64; j++) {
#pragma unroll
    for (int r = 0; r < 3; r++) K7_LOAD(wC[r], i - 1 + r, j + 1);
    float acc[4];
#pragma unroll
    for (int cc = 0; cc < 4; cc++) {
      acc[cc] = bias[cc]
        + w[0][cc] * wA[0][cc] + w[1][cc] * wB[0][cc] + w[2][cc] * wC[0][cc]
        + w[3][cc] * wA[1][cc] + w[4][cc] * wB[1][cc] + w[5][cc] * wC[1][cc]
        + w[6][cc] * wA[2][cc] + w[7][cc] * wB[2][cc] + w[8][cc] * wC[2][cc];
    }
    ushort4 u;
    u.x = f2bf(geluf(acc[0]));
    u.y = f2bf(geluf(acc[1]));
    u.z = f2bf(geluf(acc[2]));
    u.w = f2bf(geluf(acc[3]));
    *(ushort4*)(obase + ((size_t)(i * 256 + j)) * 256) = u;
#pragma unroll
    for (int r = 0; r < 3; r++) {
#pragma unroll
      for (int cc = 0; cc < 4; cc++) { wA[r][cc] = wB[r][cc]; wB[r][cc] = wC[r][cc]; }
    }
  }
#undef K7_LOAD
}

// K8: out += conv1x1(m2, 256->128) + m3_b as bf16 MFMA GEMM.
// A = packed weights w8 (m=o), B = m2 pixels from mb2 [px][c(256)] staged to LDS
// in two 128-c halves (slot swizzle). D: row=o, col=px -> fully-coalesced fp32 RMW
// (16 consecutive px per store instruction = 64B lines).
__global__ void __launch_bounds__(256) k8_m3(
    const unsigned short* __restrict__ mb2, const unsigned short* __restrict__ w8,
    const float* __restrict__ m3b, float* __restrict__ out) {
  int px0 = blockIdx.x * 128;
  int b = blockIdx.z;
  int tid = threadIdx.x;
  int wv = tid >> 6, lane = tid & 63;
  int mh = wv & 1, nh = wv >> 1;
  int l15 = lane & 15, quad = lane >> 4;
  __shared__ __align__(16) unsigned short attL[16384];  // 32KB: [n(128)][slot(16)][8]

  floatx4 acc[16];
#pragma unroll
  for (int x = 0; x < 16; x++) acc[x] = floatx4{0.f, 0.f, 0.f, 0.f};

  for (int kk = 0; kk < 2; kk++) {
    if (kk) __syncthreads();
    const unsigned short* src = mb2 + ((size_t)b * 65536 + px0) * 256 + kk * 128;
#pragma unroll
    for (int k = 0; k < 8; k++) {
      int u = k * 256 + tid;
      int n = u >> 4, ch = u & 15;
      short8 v = *(const short8*)(src + (size_t)n * 256 + ch * 8);
      int slot = ch ^ (n & 7);
      *(short8*)(attL + ((size_t)n * 16 + slot) * 8) = v;
    }
    __syncthreads();

#pragma unroll
    for (int step = 0; step < 4; step++) {
      int ch = step * 4 + quad;            // chunk within this 128-c half
      int chg = kk * 16 + ch;              // global chunk (of 32)
      short8 aw[4], bp[4];
#pragma unroll
      for (int mt = 0; mt < 4; mt++) {
        int o = mh * 64 + mt * 16 + l15;
        aw[mt] = *(const short8*)(w8 + ((size_t)chg * 128 + o) * 8);
      }
#pragma unroll
      for (int nt = 0; nt < 4; nt++) {
        int row = nh * 64 + nt * 16 + l15;
        int slot = ch ^ (row & 7);
        bp[nt] = *(const short8*)(attL + (row * 16 + slot) * 8);
      }
#pragma unroll
      for (int mt = 0; mt < 4; mt++)
#pragma unroll
        for (int nt = 0; nt < 4; nt++)
          acc[mt * 4 + nt] =
              __builtin_amdgcn_mfma_f32_16x16x32_bf16(aw[mt], bp[nt], acc[mt * 4 + nt], 0, 0, 0);
    }
  }

#pragma unroll
  for (int mt = 0; mt < 4; mt++) {
    int o0 = mh * 64 + mt * 16 + quad * 4;
    float4 bo = *(const float4*)(m3b + o0);
#pragma unroll
    for (int nt = 0; nt < 4; nt++) {
      int px = px0 + nh * 64 + nt * 16 + l15;
      floatx4 v = acc[mt * 4 + nt];
      size_t a0 = ((size_t)(b * 128 + o0 + 0)) * NHW + px;
      size_t a1 = ((size_t)(b * 128 + o0 + 1)) * NHW + px;
      size_t a2 = ((size_t)(b * 128 + o0 + 2)) * NHW + px;
      size_t a3 = ((size_t)(b * 128 + o0 + 3)) * NHW + px;
      out[a0] += v[0] + bo.x;
      out[a1] += v[1] + bo.y;
      out[a2] += v[2] + bo.z;
      out[a3] += v[3] + bo.w;
    }
  }
}

extern "C" void kernel_launch(void* const* d_in, const int* in_sizes, int n_in,
                              void* d_out, int out_size, void* d_ws, size_t ws_size,
                              hipStream_t stream) {
  const float* x1  = (const float*)d_in[0];
  const float* x2  = (const float*)d_in[1];
  const float* q1w = (const float*)d_in[2];  const float* q1b = (const float*)d_in[3];
  const float* q2w = (const float*)d_in[4];  const float* q2b = (const float*)d_in[5];
  const float* k1w = (const float*)d_in[6];  const float* k1b = (const float*)d_in[7];
  const float* k2w = (const float*)d_in[8];  const float* k2b = (const float*)d_in[9];
  const float* v1w = (const float*)d_in[10]; const float* v1b = (const float*)d_in[11];
  const float* v2w = (const float*)d_in[12]; const float* v2b = (const float*)d_in[13];
  const float* rw  = (const float*)d_in[14]; const float* rb  = (const float*)d_in[15];
  const float* m1w = (const float*)d_in[16]; const float* m1b = (const float*)d_in[17];
  const float* m2w = (const float*)d_in[18]; const float* m2b = (const float*)d_in[19];
  const float* m3w = (const float*)d_in[20]; const float* m3b = (const float*)d_in[21];
  float* ws = (float*)d_ws;
  float* out = (float*)d_out;
  unsigned short* mb  = (unsigned short*)d_ws;            // [px][o(256)] after k6
  unsigned short* mb2 = (unsigned short*)d_ws + MB2_US;   // [px][c(256)] after k7
  unsigned short* a16 = (unsigned short*)d_ws + A16_US;
  unsigned short* w6  = (unsigned short*)d_ws + W6_US;
  unsigned short* wqkv = (unsigned short*)d_ws + WQKV_US;
  unsigned short* w8  = (unsigned short*)d_ws + W8_US;    // written after k7 (dead mb region)
  unsigned short* attB = (unsigned short*)(ws + OFF_ATT);
  unsigned short* wAu  = (unsigned short*)(ws + OFF_RWT);

  (void)hipMemsetAsync((char*)d_ws + OFF_CTX * sizeof(float), 0, (4096 + 256) * sizeof(float), stream);
  k0_wprep<<<800, 256, 0, stream>>>(rw, wAu);
  k0b_w6<<<128, 256, 0, stream>>>(m1w, w6);
  k0d_wqkv<<<48, 256, 0, stream>>>(q1w, k1w, v1w, wqkv);
  k1_qkv<<<1024, 256, 0, stream>>>(x1, x2, wqkv, q1b, k1b, v1b, ws);
  k2_dw<<<dim3(16, 64, 4), 256, 0, stream>>>(ws, k2w, k2b, k1b, v2w, v2b);
  k3_ctx<<<128, 256, 0, stream>>>(ws);
  k4_att<<<512, 256, 0, stream>>>(ws, q2w, q2b, q1b);
  k5_mfma<<<dim3(256, 2, 4), 256, 0, stream>>>(attB, wAu, rb, out, a16);
  k6_m1<<<dim3(512, 2, 4), 256, 0, stream>>>(a16, w6, m1b, mb);
  k7_m2<<<dim3(256, 4), 256, 0, stream>>>(mb, m2w, m2b, mb2);
  k0c_w8<<<128, 256, 0, stream>>>(m3w, w8);
  k8_m3<<<dim3(512, 1, 4), 256, 0, stream>>>(mb2, w8, m3b, out);
}